// Round 10
// baseline (305.167 us; speedup 1.0000x reference)
//
#include <hip/hip_runtime.h>
#include <hip/hip_bf16.h>
#include <math.h>

// ---------------- workspace layout (floats) ----------------
#define WS_AT    0            // At fp32 20480 (dedicated)
#define WS_YSUM  20480        // 40
#define WS_XMAX  20520        // 8
#define WS_HIST  20528        // 816 (int)
#define WS_THR   21344        // 32 (unused now, kept for layout stability)
#define WS_MN    21376        // 40 (uint)
#define WS_MX    21440        // 40 (uint)
#define WS_XP    21504        // 8*3*256*256 = 1572864
#define WS_IA    1594368      // 8*256*256   = 524288
#define WS_XGL   2118656      // 8*256*256   = 524288
// P2 = ws + WS_XP + 20480 (1310720 floats, inside xp region, written after convgl)

#define GDM_OUT  655360       // 8*5*128*128

static __device__ __forceinline__ float xv_val(int i) {
    double t = (double)i / 100.0;
    return (float)(10.0 * t * t * t);
}

// ---- F1: fused [pool3+mean | mixA | zero/init accumulators] ----
__global__ __launch_bounds__(256) void k_front(const float* __restrict__ x,
                                               const float* __restrict__ hw,
                                               const float* __restrict__ fcw,
                                               float* __restrict__ xp,
                                               float* __restrict__ ia,
                                               float* __restrict__ At,
                                               float* __restrict__ zr,
                                               unsigned* __restrict__ mnb,
                                               unsigned* __restrict__ mxb) {
    int bid = blockIdx.x;
    if (bid < 2048) {
        int idx = bid * 256 + threadIdx.x;
        int b = idx >> 16; int p = idx & 65535; int oy = p >> 8; int ox = p & 255;
        float cs[3];
#pragma unroll
        for (int c = 0; c < 3; ++c) {
            const float* src = x + (((size_t)(b * 3 + c)) << 18);
            float s = 0.f;
#pragma unroll
            for (int dy = -1; dy <= 1; ++dy) {
                int iy = 2 * oy + dy; if ((unsigned)iy >= 512u) continue;
#pragma unroll
                for (int dx = -1; dx <= 1; ++dx) {
                    int ix = 2 * ox + dx; if ((unsigned)ix >= 512u) continue;
                    s += src[iy * 512 + ix];
                }
            }
            cs[c] = s * (1.f / 9.f);
            xp[(((size_t)(b * 3 + c)) << 16) + p] = cs[c];
        }
        ia[(((size_t)b) << 16) + p] = (cs[0] + cs[1] + cs[2]) * (1.f / 3.f);
    } else if (bid < 2128) {
        int idx = (bid - 2048) * 256 + threadIdx.x;   // 20480
        int o = idx & 63; int k = idx >> 6;           // k = d*64+c
        int d = k >> 6; int c = k & 63;
        const int goff[5] = {0, 1, 2, 3, 8};
        float s = 0.f;
        for (int m = 0; m < 64; ++m)
            s += fcw[o * 320 + d * 64 + m] * hw[(m * 64 + c) * 9 + goff[d]];
        At[k * 64 + o] = s * ((d == 4) ? 4.f : 1.f);
    } else {
#pragma unroll
        for (int q = 0; q < 4; ++q) {
            int i = threadIdx.x + 256 * q;
            if (i < 864) zr[i] = 0.f;
        }
        if (threadIdx.x < 40) mnb[threadIdx.x] = 0x7f7fffffu;
        else if (threadIdx.x < 80) mxb[threadIdx.x - 40] = 0u;
    }
}

// ---- G2+G4 merged: conv7 spatial-sum (512 blocks) | x_GL+hist+max (2048 blocks) ----
__global__ __launch_bounds__(256) void k_convgl(const float* __restrict__ xp,
                                                const float* __restrict__ w,
                                                float* __restrict__ ysum,
                                                const float* __restrict__ ia,
                                                const float* __restrict__ gdmw,
                                                float* __restrict__ xgl,
                                                int* __restrict__ hist,
                                                unsigned* __restrict__ xmax) {
    __shared__ float wsm[735];
    __shared__ float red[256];
    __shared__ float xv[101];
    __shared__ int sh[102];
    int bid = blockIdx.x;
    int tid = threadIdx.x;
    if (bid < 512) {
        // conv7x7 s2 p3, all 5 cos, spatial sum
        int b = bid >> 6;
        int p = (bid & 63) * 256 + tid;
        int oy = p >> 7, ox = p & 127;
        for (int l = tid; l < 735; l += 256) wsm[l] = w[l];
        __syncthreads();
        float s[5] = {0.f, 0.f, 0.f, 0.f, 0.f};
        for (int ic = 0; ic < 3; ++ic) {
            const float* src = xp + (((size_t)(b * 3 + ic)) << 16);
#pragma unroll
            for (int r = 0; r < 7; ++r) {
                int iy = 2 * oy - 3 + r; if ((unsigned)iy >= 256u) continue;
#pragma unroll
                for (int ss = 0; ss < 7; ++ss) {
                    int ix = 2 * ox - 3 + ss; if ((unsigned)ix >= 256u) continue;
                    float v = src[iy * 256 + ix];
                    int wi = (ic * 7 + r) * 7 + ss;
#pragma unroll
                    for (int co = 0; co < 5; ++co) s[co] = fmaf(wsm[co * 147 + wi], v, s[co]);
                }
            }
        }
#pragma unroll
        for (int co = 0; co < 5; ++co) {
            red[tid] = s[co]; __syncthreads();
            for (int off = 128; off > 0; off >>= 1) {
                if (tid < off) red[tid] += red[tid + off];
                __syncthreads();
            }
            if (tid == 0) atomicAdd(&ysum[b * 5 + co], red[0]);
            __syncthreads();
        }
    } else {
        // GL stencil + histogram + per-b max
        int idx = bid - 512;
        int b = idx >> 8;
        int p = (idx & 255) * 256 + tid;
        int y = p >> 8, x = p & 255;
        if (tid < 101) xv[tid] = xv_val(tid);
        if (tid < 102) sh[tid] = 0;
        __syncthreads();
        const float* src = ia + (((size_t)b) << 16);
        float a1 = gdmw[0] * 4.f;
        auto rd = [&](int dy, int dx) -> float {
            int iy = y + dy, ix = x + dx;
            if ((unsigned)iy >= 256u || (unsigned)ix >= 256u) return 0.f;
            return src[iy * 256 + ix];
        };
        float acc = rd(0, 0)
            - 0.125f  * (rd(-1, 0) + rd(0, -1) + rd(0, 1) + rd(1, 0))
            - 0.0625f * (rd(-2, 0) + rd(-1, -1) + rd(-1, 1) + rd(0, -2) +
                         rd(0, 2) + rd(1, -1) + rd(1, 1) + rd(2, 0));
        float raw = fabsf(a1 * acc);
        float val = (raw < 1e-6f) ? 0.f : raw;
        xgl[(((size_t)b) << 16) + p] = val;
        if (val > 0.f) {
            int lo = 0, hi = 101;
            while (lo < hi) { int mid = (lo + hi) >> 1; if (val <= xv[mid]) hi = mid; else lo = mid + 1; }
            atomicAdd(&sh[lo], 1);
        }
        red[tid] = val; __syncthreads();
        for (int off = 128; off > 0; off >>= 1) {
            if (tid < off) red[tid] = fmaxf(red[tid], red[tid + off]);
            __syncthreads();
        }
        if (tid == 0) atomicMax(&xmax[b], __float_as_uint(red[0]));
        if (tid < 102 && sh[tid]) atomicAdd(&hist[b * 102 + tid], sh[tid]);
    }
}

// ---- P1: inline thresholds + mask + h-box9 + v-box9 -> p0 [40][256][256] ----
#define F1_STR 268
__global__ __launch_bounds__(256) void k_hv1(const float* __restrict__ in,
                                             const float* __restrict__ ysum,
                                             const float* __restrict__ gamma,
                                             const float* __restrict__ beta,
                                             const float* __restrict__ mean,
                                             const float* __restrict__ var,
                                             const int* __restrict__ hist,
                                             const unsigned* __restrict__ xmax,
                                             float* __restrict__ outp) {
    int plane = blockIdx.y;
    int r0 = blockIdx.x * 8;
    int b = plane / 5, band = plane - 5 * b;
    __shared__ float sthr[4];
    int tid = threadIdx.x;
    if (tid == 0) {
        float wa[5];
        for (int c = 1; c < 5; ++c) {
            float m = ysum[b * 5 + c] * (1.f / 16384.f);
            wa[c] = tanhf((m - mean[c]) * rsqrtf(var[c] + 1e-5f) * gamma[c] + beta[c]);
        }
        float pr[4] = {0.2f + 0.05f * wa[1], 0.4f + 0.05f * wa[2],
                       0.6f + 0.05f * wa[3], 0.8f + 0.05f * wa[4]};
        auto sw = [&](int i, int j) { if (pr[i] > pr[j]) { float t = pr[i]; pr[i] = pr[j]; pr[j] = t; } };
        sw(0, 1); sw(2, 3); sw(0, 2); sw(1, 3); sw(1, 2);
        int all = 0;
        for (int i = 0; i <= 101; ++i) all += hist[b * 102 + i];
        float bestz[4] = {1e30f, 1e30f, 1e30f, 1e30f};
        int besti[4] = {0, 0, 0, 0};
        int cum = 0;
        for (int i = 0; i <= 100; ++i) {
            cum += hist[b * 102 + i];
            float pct = (float)cum / (float)all;
            for (int t = 0; t < 4; ++t) {
                float z = fabsf(pct - pr[t]);
                if (z < bestz[t]) { bestz[t] = z; besti[t] = i; }
            }
        }
        for (int t = 0; t < 4; ++t) sthr[t] = xv_val(besti[t]);
    }
    __syncthreads();
    float tmin = (band == 0) ? 0.f : sthr[band - 1];
    float tmax = (band == 4) ? __uint_as_float(xmax[b]) : sthr[band];
    const float* src = in + (((size_t)b) << 16);
    __shared__ float mr[16][F1_STR];
    __shared__ float hh[16][256];
    for (int l = tid; l < 16 * 256; l += 256) {
        int i = l >> 8, c = l & 255;
        int rr = r0 - 4 + i;
        float v = ((unsigned)rr < 256u) ? src[rr * 256 + c] : 0.f;
        v = (v > tmin && v <= tmax) ? 1.f : 0.f;
        mr[i][c + 4] = v;
    }
    if (tid < 128) { int i = tid >> 3, p = tid & 7; mr[i][p < 4 ? p : 256 + p] = 0.f; }
    __syncthreads();
    {
        int r = tid >> 4, x0 = (tid & 15) * 16;
        float w[24];
#pragma unroll
        for (int k = 0; k < 6; ++k) {
            float4 q = *(const float4*)&mr[r][x0 + 4 * k];
            w[4 * k] = q.x; w[4 * k + 1] = q.y; w[4 * k + 2] = q.z; w[4 * k + 3] = q.w;
        }
        float o[16];
        float s = 0.f;
#pragma unroll
        for (int k = 0; k < 9; ++k) s += w[k];
#pragma unroll
        for (int j = 0; j < 16; ++j) {
            o[j] = s * (1.f / 9.f);
            if (j < 15) s += w[j + 9] - w[j];
        }
#pragma unroll
        for (int k = 0; k < 4; ++k) {
            float4 q = {o[4 * k], o[4 * k + 1], o[4 * k + 2], o[4 * k + 3]};
            *(float4*)&hh[r][x0 + 4 * k] = q;
        }
    }
    __syncthreads();
    {
        int c = tid;
        float ld[16];
#pragma unroll
        for (int i = 0; i < 16; ++i) ld[i] = hh[i][c];
        float s = 0.f;
#pragma unroll
        for (int k = 0; k < 9; ++k) s += ld[k];
        float* dst = outp + (((size_t)plane) << 16);
#pragma unroll
        for (int j = 0; j < 8; ++j) {
            dst[(r0 + j) * 256 + c] = s * (1.f / 9.f);
            if (j < 7) s += ld[j + 9] - ld[j];
        }
    }
}

// ---- P2: fused pass2 (h+v) + pass3 (h_s2+v_s2) + minmax ----
__global__ __launch_bounds__(256) void k_hv2s2(const float* __restrict__ in,
                                               float* __restrict__ outp,
                                               unsigned* __restrict__ mnb,
                                               unsigned* __restrict__ mxb) {
    int plane = blockIdx.y;
    int r0 = blockIdx.x * 8;
    __shared__ float mr[31][264];
    __shared__ float hh[31][256];
    int tid = threadIdx.x;
    const float* src = in + (((size_t)plane) << 16);
    for (int l = tid; l < 31 * 264; l += 256) {
        int i = l / 264, c = l - i * 264;
        int rr = 2 * r0 - 8 + i, cc = c - 4;
        mr[i][c] = ((unsigned)rr < 256u && (unsigned)cc < 256u) ? src[rr * 256 + cc] : 0.f;
    }
    __syncthreads();
    for (int l = tid; l < 31 * 256; l += 256) {
        int i = l >> 8, x = l & 255;
        float s = 0.f;
#pragma unroll
        for (int k = 0; k < 9; ++k) s += mr[i][x + k];
        hh[i][x] = s * (1.f / 9.f);
    }
    __syncthreads();
    for (int l = tid; l < 23 * 256; l += 256) {
        int i2 = l >> 8, x = l & 255;
        float s = 0.f;
#pragma unroll
        for (int k = 0; k < 9; ++k) s += hh[i2 + k][x];
        float v = s * (1.f / 9.f);
        if ((unsigned)(2 * r0 - 4 + i2) >= 256u) v = 0.f;
        mr[i2][x + 4] = v;
    }
    if (tid < 184) { int i2 = tid / 8, p = tid & 7; mr[i2][p < 4 ? p : 256 + p] = 0.f; }
    __syncthreads();
    for (int l = tid; l < 23 * 128; l += 256) {
        int i2 = l >> 7, ox = l & 127;
        float s = 0.f;
#pragma unroll
        for (int k = 0; k < 9; ++k) s += mr[i2][2 * ox + k];
        hh[i2][ox] = s * (1.f / 9.f);
    }
    __syncthreads();
    float vmn = 1e30f, vmx = -1e30f;
    float* dst = outp + (size_t)plane * 16384;
#pragma unroll
    for (int q = 0; q < 4; ++q) {
        int l = tid + 256 * q;
        int jj = l >> 7, ox = l & 127;
        float s = 0.f;
#pragma unroll
        for (int k = 0; k < 9; ++k) s += hh[2 * jj + k][ox];
        s *= (1.f / 9.f);
        dst[(r0 + jj) * 128 + ox] = s;
        vmn = fminf(vmn, s); vmx = fmaxf(vmx, s);
    }
    __syncthreads();
    float* smn = &hh[23][0];
    float* smx = &hh[24][0];
    smn[tid] = vmn; smx[tid] = vmx; __syncthreads();
    for (int off = 128; off > 0; off >>= 1) {
        if (tid < off) {
            smn[tid] = fminf(smn[tid], smn[tid + off]);
            smx[tid] = fmaxf(smx[tid], smx[tid + off]);
        }
        __syncthreads();
    }
    if (tid == 0) {
        atomicMin(&mnb[plane], __float_as_uint(smn[0]));
        atomicMax(&mxb[plane], __float_as_uint(smx[0]));
    }
}

// ---- H2: 512 threads, output-split, 4 channels/iter (16 iters, 32 barriers),
//      + norm blocks (tile==64) folded in ----
__global__ __launch_bounds__(512, 2) void k_hge(const float* __restrict__ feat,
                                                const float* __restrict__ At,
                                                const float* __restrict__ fcb,
                                                const float* __restrict__ p2,
                                                const unsigned* __restrict__ mnb,
                                                const unsigned* __restrict__ mxb,
                                                float* __restrict__ gdm,
                                                float* __restrict__ out) {
    int tile = blockIdx.x, b = blockIdx.y;
    int tid = threadIdx.x;
    if (tile == 64) {
        // fused norm: 8 blocks x 512 threads x 40 float4 = 163840 float4
        int base = b * 512 + tid;
#pragma unroll
        for (int q = 0; q < 40; ++q) {
            int i4 = base + 4096 * q;
            int idx = i4 * 4;
            int plane = idx >> 14;
            float mn = __uint_as_float(mnb[plane]), mx = __uint_as_float(mxb[plane]);
            float inv = 1.f / (mx - mn);
            float4 v = *(const float4*)&p2[idx];
            float4 o = {(v.x - mn) * inv, (v.y - mn) * inv, (v.z - mn) * inv, (v.w - mn) * inv};
            *(float4*)&gdm[idx] = o;
        }
        return;
    }
    int ty = (tile >> 3) * 16, tx = (tile & 7) * 16;
    int grp = tid >> 8, tg = tid & 255;     // grp = output half
    __shared__ float ft[4][20][21];         //  6720 B (single buf)
    __shared__ float tl[4][5][256];         // 20480 B (single buf; barrier-protected)
    __shared__ float al[2][4][5][64];       // 10240 B (double buf)
    int og = tg >> 5, pg = tg & 31;
    float acc[8][4];                        // px = pg + 32*pj ; o = grp*32 + og*4 + oi
#pragma unroll
    for (int i = 0; i < 8; ++i)
#pragma unroll
        for (int j = 0; j < 4; ++j) acc[i][j] = 0.f;

    // staging: 1600 ft (4ch x 20x20) + 1280 al (4ch x 5d x 64o) = 2880 over 512 threads
    const float* cur[6];
    int str6[6], lof[6], typ[6];
    bool ok[6];
#pragma unroll
    for (int j = 0; j < 6; ++j) {
        int l = tid + 512 * j;
        cur[j] = nullptr; str6[j] = 0; lof[j] = 0; typ[j] = 2; ok[j] = false;
        if (l < 1600) {
            int ch = l / 400, rem = l - ch * 400;
            int r = rem / 20, cx = rem - r * 20;
            lof[j] = ch * 420 + r * 21 + cx;
            typ[j] = 0;
            int gy = ty - 2 + r, gx = tx - 2 + cx;
            if ((unsigned)gy < 128u && (unsigned)gx < 128u) {
                cur[j] = feat + (((size_t)(b * 64 + ch)) << 14) + gy * 128 + gx;
                str6[j] = 4 << 14;           // +4 channels per iteration
                ok[j] = true;
            }
        } else if (l < 2880) {
            int q = l - 1600;
            int ch = q / 320, k = q - ch * 320;          // k = d*64+o
            cur[j] = At + (k >> 6) * 4096 + ch * 64 + (k & 63);  // (d*64+c)*64+o, c=ch
            str6[j] = 256;                  // c += 4
            lof[j] = ch * 320 + k;
            typ[j] = 1;
            ok[j] = true;
        }
    }
    float pf[6];
#pragma unroll
    for (int j = 0; j < 6; ++j) pf[j] = ok[j] ? *cur[j] : 0.f;

    float* ftb = &ft[0][0][0];
    for (int g = 0; g < 16; ++g) {
        int buf = g & 1;
        float* alb = (float*)al[buf];
#pragma unroll
        for (int j = 0; j < 6; ++j) {
            if (typ[j] == 0) ftb[lof[j]] = pf[j];
            else if (typ[j] == 1) alb[lof[j]] = pf[j];
        }
        __syncthreads();
        if (g < 15) {
#pragma unroll
            for (int j = 0; j < 6; ++j) {
                if (ok[j]) { cur[j] += str6[j]; pf[j] = *cur[j]; }
            }
        }
        // stencil: 1024 (px,ch) items over 512 threads (2 each)
#pragma unroll
        for (int q = 0; q < 2; ++q) {
            int item = tid + 512 * q;
            int px = item & 255, ch = item >> 8;
            int cy = (px >> 4) + 2, cx = (px & 15) + 2;
            const float (*F)[21] = ft[ch];
            float fm2 = F[cy - 2][cx], f2p = F[cy + 2][cx];
            float fl2 = F[cy][cx - 2], fr2 = F[cy][cx + 2];
            float a  = F[cy - 1][cx - 1], bq = F[cy - 1][cx], cc = F[cy - 1][cx + 1];
            float dd = F[cy][cx - 1],     ee = F[cy][cx],     ffv = F[cy][cx + 1];
            float g_ = F[cy + 1][cx - 1], h  = F[cy + 1][cx], i2 = F[cy + 1][cx + 1];
            tl[ch][0][px] = (a + 2.f * bq + cc) - (g_ + 2.f * h + i2);
            tl[ch][1][px] = 2.f * a + bq + dd - ffv - h - 2.f * i2;
            tl[ch][2][px] = (a - cc) + 2.f * (dd - ffv) + (g_ - i2);
            tl[ch][3][px] = -bq - 2.f * cc + dd - ffv + 2.f * g_ + h;
            tl[ch][4][px] = ee - 0.125f * (bq + dd + ffv + h)
                          - 0.0625f * (fm2 + a + cc + fl2 + fr2 + g_ + i2 + f2p);
        }
        __syncthreads();
        // FMA: 8 px x 4 outs x 4 ch x 5 d
#pragma unroll
        for (int ch = 0; ch < 4; ++ch) {
#pragma unroll
            for (int d = 0; d < 5; ++d) {
                float4 a0 = *(const float4*)&al[buf][ch][d][grp * 32 + og * 4];
                float av[4] = {a0.x, a0.y, a0.z, a0.w};
#pragma unroll
                for (int pj = 0; pj < 8; ++pj) {
                    float tv = tl[ch][d][pg + 32 * pj];
#pragma unroll
                    for (int oi = 0; oi < 4; ++oi)
                        acc[pj][oi] = fmaf(av[oi], tv, acc[pj][oi]);
                }
            }
        }
    }
    // epilogue: plain stores
#pragma unroll
    for (int oi = 0; oi < 4; ++oi) {
        int o = grp * 32 + og * 4 + oi;
        float bias = fcb[o];
        float* dsto = out + (((size_t)(b * 64 + o)) << 14);
#pragma unroll
        for (int pj = 0; pj < 8; ++pj) {
            int pxl = pg + 32 * pj;
            dsto[(ty + (pxl >> 4)) * 128 + tx + (pxl & 15)] = acc[pj][oi] + bias;
        }
    }
}

extern "C" void kernel_launch(void* const* d_in, const int* in_sizes, int n_in,
                              void* d_out, int out_size, void* d_ws, size_t ws_size,
                              hipStream_t stream) {
    const float* x    = (const float*)d_in[0];
    const float* gdmw = (const float*)d_in[1];
    const float* convw= (const float*)d_in[2];
    const float* bng  = (const float*)d_in[3];
    const float* bnb  = (const float*)d_in[4];
    const float* bnm  = (const float*)d_in[5];
    const float* bnv  = (const float*)d_in[6];
    const float* feat = (const float*)d_in[7];
    const float* hw   = (const float*)d_in[8];
    const float* fcw  = (const float*)d_in[9];
    const float* fcb  = (const float*)d_in[10];
    float* out = (float*)d_out;
    float* ws  = (float*)d_ws;

    float* At   = ws + WS_AT;
    float* ysum = ws + WS_YSUM;
    unsigned* xmax = (unsigned*)(ws + WS_XMAX);
    int* hist   = (int*)(ws + WS_HIST);
    unsigned* mnb = (unsigned*)(ws + WS_MN);
    unsigned* mxb = (unsigned*)(ws + WS_MX);
    float* xp   = ws + WS_XP;
    float* ia   = ws + WS_IA;
    float* xgl  = ws + WS_XGL;
    float* p2   = ws + WS_XP + 20480;

    float* hge = out + GDM_OUT;
    float* p0  = hge;                    // pool scratch in hge region (overwritten by k_hge)

    k_front  <<<2129, 256, 0, stream>>>(x, hw, fcw, xp, ia, At, ws + WS_YSUM, mnb, mxb);
    k_convgl <<<2560, 256, 0, stream>>>(xp, convw, ysum, ia, gdmw, xgl, hist, xmax);
    k_hv1    <<<dim3(32, 40), 256, 0, stream>>>(xgl, ysum, bng, bnb, bnm, bnv, hist, xmax, p0);
    k_hv2s2  <<<dim3(16, 40), 256, 0, stream>>>(p0, p2, mnb, mxb);
    k_hge    <<<dim3(65, 8), 512, 0, stream>>>(feat, At, fcb, p2, mnb, mxb, out, hge);
}

// Round 11
// 284.171 us; speedup vs baseline: 1.0739x; 1.0739x over previous
//
#include <hip/hip_runtime.h>
#include <hip/hip_bf16.h>
#include <math.h>

// ---------------- workspace layout (floats) ----------------
#define WS_AT    0            // At fp32 20480 (dedicated)
#define WS_YSUM  20480        // 40
#define WS_XMAX  20520        // 8
#define WS_HIST  20528        // 816 (int)
#define WS_MN    21376        // 40 (uint)
#define WS_MX    21440        // 40 (uint)
#define WS_XP    21504        // 8*3*256*256 = 1572864
#define WS_IA    1594368      // 8*256*256   = 524288
#define WS_XGL   2118656      // 8*256*256   = 524288
// P2 = ws + WS_XP + 20480 (1310720 floats, inside xp region, written after convgl)

#define GDM_OUT  655360       // 8*5*128*128

static __device__ __forceinline__ float xv_val(int i) {
    double t = (double)i / 100.0;
    return (float)(10.0 * t * t * t);
}

// ---- F1: fused [pool3+mean | mixA | zero/init accumulators] ----
__global__ __launch_bounds__(256) void k_front(const float* __restrict__ x,
                                               const float* __restrict__ hw,
                                               const float* __restrict__ fcw,
                                               float* __restrict__ xp,
                                               float* __restrict__ ia,
                                               float* __restrict__ At,
                                               float* __restrict__ zr,
                                               unsigned* __restrict__ mnb,
                                               unsigned* __restrict__ mxb) {
    int bid = blockIdx.x;
    if (bid < 2048) {
        int idx = bid * 256 + threadIdx.x;
        int b = idx >> 16; int p = idx & 65535; int oy = p >> 8; int ox = p & 255;
        float cs[3];
#pragma unroll
        for (int c = 0; c < 3; ++c) {
            const float* src = x + (((size_t)(b * 3 + c)) << 18);
            float s = 0.f;
#pragma unroll
            for (int dy = -1; dy <= 1; ++dy) {
                int iy = 2 * oy + dy; if ((unsigned)iy >= 512u) continue;
#pragma unroll
                for (int dx = -1; dx <= 1; ++dx) {
                    int ix = 2 * ox + dx; if ((unsigned)ix >= 512u) continue;
                    s += src[iy * 512 + ix];
                }
            }
            cs[c] = s * (1.f / 9.f);
            xp[(((size_t)(b * 3 + c)) << 16) + p] = cs[c];
        }
        ia[(((size_t)b) << 16) + p] = (cs[0] + cs[1] + cs[2]) * (1.f / 3.f);
    } else if (bid < 2128) {
        int idx = (bid - 2048) * 256 + threadIdx.x;   // 20480
        int o = idx & 63; int k = idx >> 6;           // k = d*64+c
        int d = k >> 6; int c = k & 63;
        const int goff[5] = {0, 1, 2, 3, 8};
        float s = 0.f;
        for (int m = 0; m < 64; ++m)
            s += fcw[o * 320 + d * 64 + m] * hw[(m * 64 + c) * 9 + goff[d]];
        At[k * 64 + o] = s * ((d == 4) ? 4.f : 1.f);
    } else {
#pragma unroll
        for (int q = 0; q < 4; ++q) {
            int i = threadIdx.x + 256 * q;
            if (i < 864) zr[i] = 0.f;
        }
        if (threadIdx.x < 40) mnb[threadIdx.x] = 0x7f7fffffu;
        else if (threadIdx.x < 80) mxb[threadIdx.x - 40] = 0u;
    }
}

// ---- G2+G4 merged: conv7 spatial-sum (512 blocks) | x_GL+hist+max (2048 blocks) ----
__global__ __launch_bounds__(256) void k_convgl(const float* __restrict__ xp,
                                                const float* __restrict__ w,
                                                float* __restrict__ ysum,
                                                const float* __restrict__ ia,
                                                const float* __restrict__ gdmw,
                                                float* __restrict__ xgl,
                                                int* __restrict__ hist,
                                                unsigned* __restrict__ xmax) {
    __shared__ float wsm[735];
    __shared__ float red[256];
    __shared__ float xv[101];
    __shared__ int sh[102];
    int bid = blockIdx.x;
    int tid = threadIdx.x;
    if (bid < 512) {
        int b = bid >> 6;
        int p = (bid & 63) * 256 + tid;
        int oy = p >> 7, ox = p & 127;
        for (int l = tid; l < 735; l += 256) wsm[l] = w[l];
        __syncthreads();
        float s[5] = {0.f, 0.f, 0.f, 0.f, 0.f};
        for (int ic = 0; ic < 3; ++ic) {
            const float* src = xp + (((size_t)(b * 3 + ic)) << 16);
#pragma unroll
            for (int r = 0; r < 7; ++r) {
                int iy = 2 * oy - 3 + r; if ((unsigned)iy >= 256u) continue;
#pragma unroll
                for (int ss = 0; ss < 7; ++ss) {
                    int ix = 2 * ox - 3 + ss; if ((unsigned)ix >= 256u) continue;
                    float v = src[iy * 256 + ix];
                    int wi = (ic * 7 + r) * 7 + ss;
#pragma unroll
                    for (int co = 0; co < 5; ++co) s[co] = fmaf(wsm[co * 147 + wi], v, s[co]);
                }
            }
        }
#pragma unroll
        for (int co = 0; co < 5; ++co) {
            red[tid] = s[co]; __syncthreads();
            for (int off = 128; off > 0; off >>= 1) {
                if (tid < off) red[tid] += red[tid + off];
                __syncthreads();
            }
            if (tid == 0) atomicAdd(&ysum[b * 5 + co], red[0]);
            __syncthreads();
        }
    } else {
        int idx = bid - 512;
        int b = idx >> 8;
        int p = (idx & 255) * 256 + tid;
        int y = p >> 8, x = p & 255;
        if (tid < 101) xv[tid] = xv_val(tid);
        if (tid < 102) sh[tid] = 0;
        __syncthreads();
        const float* src = ia + (((size_t)b) << 16);
        float a1 = gdmw[0] * 4.f;
        auto rd = [&](int dy, int dx) -> float {
            int iy = y + dy, ix = x + dx;
            if ((unsigned)iy >= 256u || (unsigned)ix >= 256u) return 0.f;
            return src[iy * 256 + ix];
        };
        float acc = rd(0, 0)
            - 0.125f  * (rd(-1, 0) + rd(0, -1) + rd(0, 1) + rd(1, 0))
            - 0.0625f * (rd(-2, 0) + rd(-1, -1) + rd(-1, 1) + rd(0, -2) +
                         rd(0, 2) + rd(1, -1) + rd(1, 1) + rd(2, 0));
        float raw = fabsf(a1 * acc);
        float val = (raw < 1e-6f) ? 0.f : raw;
        xgl[(((size_t)b) << 16) + p] = val;
        if (val > 0.f) {
            int lo = 0, hi = 101;
            while (lo < hi) { int mid = (lo + hi) >> 1; if (val <= xv[mid]) hi = mid; else lo = mid + 1; }
            atomicAdd(&sh[lo], 1);
        }
        red[tid] = val; __syncthreads();
        for (int off = 128; off > 0; off >>= 1) {
            if (tid < off) red[tid] = fmaxf(red[tid], red[tid + off]);
            __syncthreads();
        }
        if (tid == 0) atomicMax(&xmax[b], __float_as_uint(red[0]));
        if (tid < 102 && sh[tid]) atomicAdd(&hist[b * 102 + tid], sh[tid]);
    }
}

// ---- P1: inline thresholds + mask + h-box9 + v-box9 -> p0 [40][256][256] ----
#define F1_STR 268
__global__ __launch_bounds__(256) void k_hv1(const float* __restrict__ in,
                                             const float* __restrict__ ysum,
                                             const float* __restrict__ gamma,
                                             const float* __restrict__ beta,
                                             const float* __restrict__ mean,
                                             const float* __restrict__ var,
                                             const int* __restrict__ hist,
                                             const unsigned* __restrict__ xmax,
                                             float* __restrict__ outp) {
    int plane = blockIdx.y;
    int r0 = blockIdx.x * 8;
    int b = plane / 5, band = plane - 5 * b;
    __shared__ float sthr[4];
    int tid = threadIdx.x;
    if (tid == 0) {
        float wa[5];
        for (int c = 1; c < 5; ++c) {
            float m = ysum[b * 5 + c] * (1.f / 16384.f);
            wa[c] = tanhf((m - mean[c]) * rsqrtf(var[c] + 1e-5f) * gamma[c] + beta[c]);
        }
        float pr[4] = {0.2f + 0.05f * wa[1], 0.4f + 0.05f * wa[2],
                       0.6f + 0.05f * wa[3], 0.8f + 0.05f * wa[4]};
        auto sw = [&](int i, int j) { if (pr[i] > pr[j]) { float t = pr[i]; pr[i] = pr[j]; pr[j] = t; } };
        sw(0, 1); sw(2, 3); sw(0, 2); sw(1, 3); sw(1, 2);
        int all = 0;
        for (int i = 0; i <= 101; ++i) all += hist[b * 102 + i];
        float bestz[4] = {1e30f, 1e30f, 1e30f, 1e30f};
        int besti[4] = {0, 0, 0, 0};
        int cum = 0;
        for (int i = 0; i <= 100; ++i) {
            cum += hist[b * 102 + i];
            float pct = (float)cum / (float)all;
            for (int t = 0; t < 4; ++t) {
                float z = fabsf(pct - pr[t]);
                if (z < bestz[t]) { bestz[t] = z; besti[t] = i; }
            }
        }
        for (int t = 0; t < 4; ++t) sthr[t] = xv_val(besti[t]);
    }
    __syncthreads();
    float tmin = (band == 0) ? 0.f : sthr[band - 1];
    float tmax = (band == 4) ? __uint_as_float(xmax[b]) : sthr[band];
    const float* src = in + (((size_t)b) << 16);
    __shared__ float mr[16][F1_STR];
    __shared__ float hh[16][256];
    for (int l = tid; l < 16 * 256; l += 256) {
        int i = l >> 8, c = l & 255;
        int rr = r0 - 4 + i;
        float v = ((unsigned)rr < 256u) ? src[rr * 256 + c] : 0.f;
        v = (v > tmin && v <= tmax) ? 1.f : 0.f;
        mr[i][c + 4] = v;
    }
    if (tid < 128) { int i = tid >> 3, p = tid & 7; mr[i][p < 4 ? p : 256 + p] = 0.f; }
    __syncthreads();
    {
        int r = tid >> 4, x0 = (tid & 15) * 16;
        float w[24];
#pragma unroll
        for (int k = 0; k < 6; ++k) {
            float4 q = *(const float4*)&mr[r][x0 + 4 * k];
            w[4 * k] = q.x; w[4 * k + 1] = q.y; w[4 * k + 2] = q.z; w[4 * k + 3] = q.w;
        }
        float o[16];
        float s = 0.f;
#pragma unroll
        for (int k = 0; k < 9; ++k) s += w[k];
#pragma unroll
        for (int j = 0; j < 16; ++j) {
            o[j] = s * (1.f / 9.f);
            if (j < 15) s += w[j + 9] - w[j];
        }
#pragma unroll
        for (int k = 0; k < 4; ++k) {
            float4 q = {o[4 * k], o[4 * k + 1], o[4 * k + 2], o[4 * k + 3]};
            *(float4*)&hh[r][x0 + 4 * k] = q;
        }
    }
    __syncthreads();
    {
        int c = tid;
        float ld[16];
#pragma unroll
        for (int i = 0; i < 16; ++i) ld[i] = hh[i][c];
        float s = 0.f;
#pragma unroll
        for (int k = 0; k < 9; ++k) s += ld[k];
        float* dst = outp + (((size_t)plane) << 16);
#pragma unroll
        for (int j = 0; j < 8; ++j) {
            dst[(r0 + j) * 256 + c] = s * (1.f / 9.f);
            if (j < 7) s += ld[j + 9] - ld[j];
        }
    }
}

// ---- P2: fused pass2 (h+v) + pass3 (h_s2+v_s2) + minmax ----
__global__ __launch_bounds__(256) void k_hv2s2(const float* __restrict__ in,
                                               float* __restrict__ outp,
                                               unsigned* __restrict__ mnb,
                                               unsigned* __restrict__ mxb) {
    int plane = blockIdx.y;
    int r0 = blockIdx.x * 8;
    __shared__ float mr[31][264];
    __shared__ float hh[31][256];
    int tid = threadIdx.x;
    const float* src = in + (((size_t)plane) << 16);
    for (int l = tid; l < 31 * 264; l += 256) {
        int i = l / 264, c = l - i * 264;
        int rr = 2 * r0 - 8 + i, cc = c - 4;
        mr[i][c] = ((unsigned)rr < 256u && (unsigned)cc < 256u) ? src[rr * 256 + cc] : 0.f;
    }
    __syncthreads();
    for (int l = tid; l < 31 * 256; l += 256) {
        int i = l >> 8, x = l & 255;
        float s = 0.f;
#pragma unroll
        for (int k = 0; k < 9; ++k) s += mr[i][x + k];
        hh[i][x] = s * (1.f / 9.f);
    }
    __syncthreads();
    for (int l = tid; l < 23 * 256; l += 256) {
        int i2 = l >> 8, x = l & 255;
        float s = 0.f;
#pragma unroll
        for (int k = 0; k < 9; ++k) s += hh[i2 + k][x];
        float v = s * (1.f / 9.f);
        if ((unsigned)(2 * r0 - 4 + i2) >= 256u) v = 0.f;
        mr[i2][x + 4] = v;
    }
    if (tid < 184) { int i2 = tid / 8, p = tid & 7; mr[i2][p < 4 ? p : 256 + p] = 0.f; }
    __syncthreads();
    for (int l = tid; l < 23 * 128; l += 256) {
        int i2 = l >> 7, ox = l & 127;
        float s = 0.f;
#pragma unroll
        for (int k = 0; k < 9; ++k) s += mr[i2][2 * ox + k];
        hh[i2][ox] = s * (1.f / 9.f);
    }
    __syncthreads();
    float vmn = 1e30f, vmx = -1e30f;
    float* dst = outp + (size_t)plane * 16384;
#pragma unroll
    for (int q = 0; q < 4; ++q) {
        int l = tid + 256 * q;
        int jj = l >> 7, ox = l & 127;
        float s = 0.f;
#pragma unroll
        for (int k = 0; k < 9; ++k) s += hh[2 * jj + k][ox];
        s *= (1.f / 9.f);
        dst[(r0 + jj) * 128 + ox] = s;
        vmn = fminf(vmn, s); vmx = fmaxf(vmx, s);
    }
    __syncthreads();
    float* smn = &hh[23][0];
    float* smx = &hh[24][0];
    smn[tid] = vmn; smx[tid] = vmx; __syncthreads();
    for (int off = 128; off > 0; off >>= 1) {
        if (tid < off) {
            smn[tid] = fminf(smn[tid], smn[tid + off]);
            smx[tid] = fmaxf(smx[tid], smx[tid + off]);
        }
        __syncthreads();
    }
    if (tid == 0) {
        atomicMin(&mnb[plane], __float_as_uint(smn[0]));
        atomicMax(&mxb[plane], __float_as_uint(smx[0]));
    }
}

// ---- H2: px-owner structure. 512 threads: thread = (px = tid&255, half = tid>>8).
//      Per iter (2 ch): stage ft/al (dbuf) -> ONE barrier -> in-register stencil for own px
//      -> FMA vs broadcast al reads. acc = 32 VGPR. Norm folded at tile==64. ----
__global__ __launch_bounds__(512, 2) void k_hge(const float* __restrict__ feat,
                                                const float* __restrict__ At,
                                                const float* __restrict__ fcb,
                                                const float* __restrict__ p2,
                                                const unsigned* __restrict__ mnb,
                                                const unsigned* __restrict__ mxb,
                                                float* __restrict__ gdm,
                                                float* __restrict__ out) {
    int tile = blockIdx.x, b = blockIdx.y;
    int tid = threadIdx.x;
    if (tile == 64) {
        int base = b * 512 + tid;
#pragma unroll
        for (int q = 0; q < 40; ++q) {
            int i4 = base + 4096 * q;
            int idx = i4 * 4;
            int plane = idx >> 14;
            float mn = __uint_as_float(mnb[plane]), mx = __uint_as_float(mxb[plane]);
            float inv = 1.f / (mx - mn);
            float4 v = *(const float4*)&p2[idx];
            float4 o = {(v.x - mn) * inv, (v.y - mn) * inv, (v.z - mn) * inv, (v.w - mn) * inv};
            *(float4*)&gdm[idx] = o;
        }
        return;
    }
    int ty = (tile >> 3) * 16, tx = (tile & 7) * 16;
    int px = tid & 255, half = tid >> 8;
    int py = px >> 4, pxc = px & 15;
    __shared__ float ft[2][2][20][21];   // [buf][ch][r][c]  6720 B
    __shared__ float al[2][2][5][64];    // [buf][ch][d][o]  5120 B
    float4 acc[8];                       // 32 outs: o = half*32 + o4*4 + comp
#pragma unroll
    for (int i = 0; i < 8; ++i) acc[i] = (float4){0.f, 0.f, 0.f, 0.f};

    // staging descriptors (r9-verified pattern): 800 ft + 640 al = 1440 over 512 threads
    const float* cur[3];
    int str3[3], lof[3], typ[3];
    bool ok[3];
#pragma unroll
    for (int j = 0; j < 3; ++j) {
        int l = tid + 512 * j;
        cur[j] = nullptr; str3[j] = 0; lof[j] = 0; typ[j] = 2; ok[j] = false;
        if (l < 800) {
            int ch = (l >= 400); int rem = l - ch * 400;
            int r = rem / 20, cx = rem - r * 20;
            lof[j] = ch * 420 + r * 21 + cx;
            typ[j] = 0;
            int gy = ty - 2 + r, gx = tx - 2 + cx;
            if ((unsigned)gy < 128u && (unsigned)gx < 128u) {
                cur[j] = feat + (((size_t)(b * 64 + ch)) << 14) + gy * 128 + gx;
                str3[j] = 2 << 14;           // +2 channels per iteration
                ok[j] = true;
            }
        } else if (l < 1440) {
            int q = l - 800;
            int ch = (q >= 320); int k = q - ch * 320;   // k = d*64+o
            cur[j] = At + (k >> 6) * 4096 + ch * 64 + (k & 63);  // (d*64+c)*64+o, c=ch
            str3[j] = 128;                   // c += 2
            lof[j] = ch * 320 + k;
            typ[j] = 1;
            ok[j] = true;
        }
    }
    float pf[3];
#pragma unroll
    for (int j = 0; j < 3; ++j) pf[j] = ok[j] ? *cur[j] : 0.f;

    int cy = py + 2, cx = pxc + 2;
    for (int g = 0; g < 32; ++g) {
        int buf = g & 1;
        float* ftb = &ft[buf][0][0][0];
        float* alb = &al[buf][0][0][0];
#pragma unroll
        for (int j = 0; j < 3; ++j) {
            if (typ[j] == 0) ftb[lof[j]] = pf[j];
            else if (typ[j] == 1) alb[lof[j]] = pf[j];
        }
        __syncthreads();                     // the ONLY barrier per iteration
        if (g < 31) {
#pragma unroll
            for (int j = 0; j < 3; ++j) {
                if (ok[j]) { cur[j] += str3[j]; pf[j] = *cur[j]; }
            }
        }
        // in-register stencil for own px, both channels, then FMA with broadcast al
#pragma unroll
        for (int ch = 0; ch < 2; ++ch) {
            const float (*F)[21] = ft[buf][ch];
            float u2 = F[cy - 2][cx], d2 = F[cy + 2][cx];
            float l2 = F[cy][cx - 2], r2 = F[cy][cx + 2];
            float a  = F[cy - 1][cx - 1], bq = F[cy - 1][cx], cc = F[cy - 1][cx + 1];
            float dd = F[cy][cx - 1],     ee = F[cy][cx],     fv = F[cy][cx + 1];
            float g_ = F[cy + 1][cx - 1], h  = F[cy + 1][cx], i2 = F[cy + 1][cx + 1];
            float s[5];
            s[0] = (a + 2.f * bq + cc) - (g_ + 2.f * h + i2);
            s[1] = 2.f * a + bq + dd - fv - h - 2.f * i2;
            s[2] = (a - cc) + 2.f * (dd - fv) + (g_ - i2);
            s[3] = -bq - 2.f * cc + dd - fv + 2.f * g_ + h;
            s[4] = ee - 0.125f * (bq + dd + fv + h)
                 - 0.0625f * (u2 + a + cc + l2 + r2 + g_ + i2 + d2);
#pragma unroll
            for (int d = 0; d < 5; ++d) {
                float sv = s[d];
#pragma unroll
                for (int o4 = 0; o4 < 8; ++o4) {
                    float4 av = *(const float4*)&al[buf][ch][d][half * 32 + o4 * 4];
                    acc[o4].x = fmaf(av.x, sv, acc[o4].x);
                    acc[o4].y = fmaf(av.y, sv, acc[o4].y);
                    acc[o4].z = fmaf(av.z, sv, acc[o4].z);
                    acc[o4].w = fmaf(av.w, sv, acc[o4].w);
                }
            }
        }
    }
    // epilogue: thread stores its px for its 32 outputs (coalesced across lanes)
    int yy = ty + py, xx = tx + pxc;
#pragma unroll
    for (int o4 = 0; o4 < 8; ++o4) {
        float v[4] = {acc[o4].x, acc[o4].y, acc[o4].z, acc[o4].w};
#pragma unroll
        for (int comp = 0; comp < 4; ++comp) {
            int o = half * 32 + o4 * 4 + comp;
            out[(((size_t)(b * 64 + o)) << 14) + yy * 128 + xx] = v[comp] + fcb[o];
        }
    }
}

extern "C" void kernel_launch(void* const* d_in, const int* in_sizes, int n_in,
                              void* d_out, int out_size, void* d_ws, size_t ws_size,
                              hipStream_t stream) {
    const float* x    = (const float*)d_in[0];
    const float* gdmw = (const float*)d_in[1];
    const float* convw= (const float*)d_in[2];
    const float* bng  = (const float*)d_in[3];
    const float* bnb  = (const float*)d_in[4];
    const float* bnm  = (const float*)d_in[5];
    const float* bnv  = (const float*)d_in[6];
    const float* feat = (const float*)d_in[7];
    const float* hw   = (const float*)d_in[8];
    const float* fcw  = (const float*)d_in[9];
    const float* fcb  = (const float*)d_in[10];
    float* out = (float*)d_out;
    float* ws  = (float*)d_ws;

    float* At   = ws + WS_AT;
    float* ysum = ws + WS_YSUM;
    unsigned* xmax = (unsigned*)(ws + WS_XMAX);
    int* hist   = (int*)(ws + WS_HIST);
    unsigned* mnb = (unsigned*)(ws + WS_MN);
    unsigned* mxb = (unsigned*)(ws + WS_MX);
    float* xp   = ws + WS_XP;
    float* ia   = ws + WS_IA;
    float* xgl  = ws + WS_XGL;
    float* p2   = ws + WS_XP + 20480;

    float* hge = out + GDM_OUT;
    float* p0  = hge;                    // pool scratch in hge region (overwritten by k_hge)

    k_front  <<<2129, 256, 0, stream>>>(x, hw, fcw, xp, ia, At, ws + WS_YSUM, mnb, mxb);
    k_convgl <<<2560, 256, 0, stream>>>(xp, convw, ysum, ia, gdmw, xgl, hist, xmax);
    k_hv1    <<<dim3(32, 40), 256, 0, stream>>>(xgl, ysum, bng, bnb, bnm, bnv, hist, xmax, p0);
    k_hv2s2  <<<dim3(16, 40), 256, 0, stream>>>(p0, p2, mnb, mxb);
    k_hge    <<<dim3(65, 8), 512, 0, stream>>>(feat, At, fcb, p2, mnb, mxb, out, hge);
}

// Round 12
// 256.164 us; speedup vs baseline: 1.1913x; 1.1093x over previous
//
#include <hip/hip_runtime.h>
#include <hip/hip_bf16.h>
#include <math.h>

// ---------------- workspace layout (floats) ----------------
#define WS_AT    0            // At fp32 20480 (dedicated)
#define WS_YSUM  20480        // 40
#define WS_XMAX  20520        // 8
#define WS_HIST  20528        // 816 (int)
#define WS_MN    21376        // 40 (uint)
#define WS_MX    21440        // 40 (uint)
#define WS_XP    21504        // 8*3*256*256 = 1572864
#define WS_IA    1594368      // 8*256*256   = 524288
#define WS_XGL   2118656      // 8*256*256   = 524288
// P2 = ws + WS_XP + 20480 (1310720 floats, inside xp region, written after convgl)

#define GDM_OUT  655360       // 8*5*128*128

static __device__ __forceinline__ float xv_val(int i) {
    double t = (double)i / 100.0;
    return (float)(10.0 * t * t * t);
}

// ---- F1: fused [pool3+mean | mixA | zero/init accumulators] ----
__global__ __launch_bounds__(256) void k_front(const float* __restrict__ x,
                                               const float* __restrict__ hw,
                                               const float* __restrict__ fcw,
                                               float* __restrict__ xp,
                                               float* __restrict__ ia,
                                               float* __restrict__ At,
                                               float* __restrict__ zr,
                                               unsigned* __restrict__ mnb,
                                               unsigned* __restrict__ mxb) {
    int bid = blockIdx.x;
    if (bid < 2048) {
        int idx = bid * 256 + threadIdx.x;
        int b = idx >> 16; int p = idx & 65535; int oy = p >> 8; int ox = p & 255;
        float cs[3];
#pragma unroll
        for (int c = 0; c < 3; ++c) {
            const float* src = x + (((size_t)(b * 3 + c)) << 18);
            float s = 0.f;
#pragma unroll
            for (int dy = -1; dy <= 1; ++dy) {
                int iy = 2 * oy + dy; if ((unsigned)iy >= 512u) continue;
#pragma unroll
                for (int dx = -1; dx <= 1; ++dx) {
                    int ix = 2 * ox + dx; if ((unsigned)ix >= 512u) continue;
                    s += src[iy * 512 + ix];
                }
            }
            cs[c] = s * (1.f / 9.f);
            xp[(((size_t)(b * 3 + c)) << 16) + p] = cs[c];
        }
        ia[(((size_t)b) << 16) + p] = (cs[0] + cs[1] + cs[2]) * (1.f / 3.f);
    } else if (bid < 2128) {
        int idx = (bid - 2048) * 256 + threadIdx.x;   // 20480
        int o = idx & 63; int k = idx >> 6;           // k = d*64+c
        int d = k >> 6; int c = k & 63;
        const int goff[5] = {0, 1, 2, 3, 8};
        float s = 0.f;
        for (int m = 0; m < 64; ++m)
            s += fcw[o * 320 + d * 64 + m] * hw[(m * 64 + c) * 9 + goff[d]];
        At[k * 64 + o] = s * ((d == 4) ? 4.f : 1.f);
    } else {
#pragma unroll
        for (int q = 0; q < 4; ++q) {
            int i = threadIdx.x + 256 * q;
            if (i < 864) zr[i] = 0.f;
        }
        if (threadIdx.x < 40) mnb[threadIdx.x] = 0x7f7fffffu;
        else if (threadIdx.x < 80) mxb[threadIdx.x - 40] = 0u;
    }
}

// ---- G2+G4 merged: conv7 spatial-sum (512 blocks) | x_GL+hist+max (2048 blocks) ----
__global__ __launch_bounds__(256) void k_convgl(const float* __restrict__ xp,
                                                const float* __restrict__ w,
                                                float* __restrict__ ysum,
                                                const float* __restrict__ ia,
                                                const float* __restrict__ gdmw,
                                                float* __restrict__ xgl,
                                                int* __restrict__ hist,
                                                unsigned* __restrict__ xmax) {
    __shared__ float wsm[735];
    __shared__ float red[256];
    __shared__ float xv[101];
    __shared__ int sh[102];
    int bid = blockIdx.x;
    int tid = threadIdx.x;
    if (bid < 512) {
        int b = bid >> 6;
        int p = (bid & 63) * 256 + tid;
        int oy = p >> 7, ox = p & 127;
        for (int l = tid; l < 735; l += 256) wsm[l] = w[l];
        __syncthreads();
        float s[5] = {0.f, 0.f, 0.f, 0.f, 0.f};
        for (int ic = 0; ic < 3; ++ic) {
            const float* src = xp + (((size_t)(b * 3 + ic)) << 16);
#pragma unroll
            for (int r = 0; r < 7; ++r) {
                int iy = 2 * oy - 3 + r; if ((unsigned)iy >= 256u) continue;
#pragma unroll
                for (int ss = 0; ss < 7; ++ss) {
                    int ix = 2 * ox - 3 + ss; if ((unsigned)ix >= 256u) continue;
                    float v = src[iy * 256 + ix];
                    int wi = (ic * 7 + r) * 7 + ss;
#pragma unroll
                    for (int co = 0; co < 5; ++co) s[co] = fmaf(wsm[co * 147 + wi], v, s[co]);
                }
            }
        }
#pragma unroll
        for (int co = 0; co < 5; ++co) {
            red[tid] = s[co]; __syncthreads();
            for (int off = 128; off > 0; off >>= 1) {
                if (tid < off) red[tid] += red[tid + off];
                __syncthreads();
            }
            if (tid == 0) atomicAdd(&ysum[b * 5 + co], red[0]);
            __syncthreads();
        }
    } else {
        int idx = bid - 512;
        int b = idx >> 8;
        int p = (idx & 255) * 256 + tid;
        int y = p >> 8, x = p & 255;
        if (tid < 101) xv[tid] = xv_val(tid);
        if (tid < 102) sh[tid] = 0;
        __syncthreads();
        const float* src = ia + (((size_t)b) << 16);
        float a1 = gdmw[0] * 4.f;
        auto rd = [&](int dy, int dx) -> float {
            int iy = y + dy, ix = x + dx;
            if ((unsigned)iy >= 256u || (unsigned)ix >= 256u) return 0.f;
            return src[iy * 256 + ix];
        };
        float acc = rd(0, 0)
            - 0.125f  * (rd(-1, 0) + rd(0, -1) + rd(0, 1) + rd(1, 0))
            - 0.0625f * (rd(-2, 0) + rd(-1, -1) + rd(-1, 1) + rd(0, -2) +
                         rd(0, 2) + rd(1, -1) + rd(1, 1) + rd(2, 0));
        float raw = fabsf(a1 * acc);
        float val = (raw < 1e-6f) ? 0.f : raw;
        xgl[(((size_t)b) << 16) + p] = val;
        if (val > 0.f) {
            int lo = 0, hi = 101;
            while (lo < hi) { int mid = (lo + hi) >> 1; if (val <= xv[mid]) hi = mid; else lo = mid + 1; }
            atomicAdd(&sh[lo], 1);
        }
        red[tid] = val; __syncthreads();
        for (int off = 128; off > 0; off >>= 1) {
            if (tid < off) red[tid] = fmaxf(red[tid], red[tid + off]);
            __syncthreads();
        }
        if (tid == 0) atomicMax(&xmax[b], __float_as_uint(red[0]));
        if (tid < 102 && sh[tid]) atomicAdd(&hist[b * 102 + tid], sh[tid]);
    }
}

// ---- P1: inline thresholds + mask + h-box9 + v-box9 -> p0 [40][256][256] ----
#define F1_STR 268
__global__ __launch_bounds__(256) void k_hv1(const float* __restrict__ in,
                                             const float* __restrict__ ysum,
                                             const float* __restrict__ gamma,
                                             const float* __restrict__ beta,
                                             const float* __restrict__ mean,
                                             const float* __restrict__ var,
                                             const int* __restrict__ hist,
                                             const unsigned* __restrict__ xmax,
                                             float* __restrict__ outp) {
    int plane = blockIdx.y;
    int r0 = blockIdx.x * 8;
    int b = plane / 5, band = plane - 5 * b;
    __shared__ float sthr[4];
    int tid = threadIdx.x;
    if (tid == 0) {
        float wa[5];
        for (int c = 1; c < 5; ++c) {
            float m = ysum[b * 5 + c] * (1.f / 16384.f);
            wa[c] = tanhf((m - mean[c]) * rsqrtf(var[c] + 1e-5f) * gamma[c] + beta[c]);
        }
        float pr[4] = {0.2f + 0.05f * wa[1], 0.4f + 0.05f * wa[2],
                       0.6f + 0.05f * wa[3], 0.8f + 0.05f * wa[4]};
        auto sw = [&](int i, int j) { if (pr[i] > pr[j]) { float t = pr[i]; pr[i] = pr[j]; pr[j] = t; } };
        sw(0, 1); sw(2, 3); sw(0, 2); sw(1, 3); sw(1, 2);
        int all = 0;
        for (int i = 0; i <= 101; ++i) all += hist[b * 102 + i];
        float bestz[4] = {1e30f, 1e30f, 1e30f, 1e30f};
        int besti[4] = {0, 0, 0, 0};
        int cum = 0;
        for (int i = 0; i <= 100; ++i) {
            cum += hist[b * 102 + i];
            float pct = (float)cum / (float)all;
            for (int t = 0; t < 4; ++t) {
                float z = fabsf(pct - pr[t]);
                if (z < bestz[t]) { bestz[t] = z; besti[t] = i; }
            }
        }
        for (int t = 0; t < 4; ++t) sthr[t] = xv_val(besti[t]);
    }
    __syncthreads();
    float tmin = (band == 0) ? 0.f : sthr[band - 1];
    float tmax = (band == 4) ? __uint_as_float(xmax[b]) : sthr[band];
    const float* src = in + (((size_t)b) << 16);
    __shared__ float mr[16][F1_STR];
    __shared__ float hh[16][256];
    for (int l = tid; l < 16 * 256; l += 256) {
        int i = l >> 8, c = l & 255;
        int rr = r0 - 4 + i;
        float v = ((unsigned)rr < 256u) ? src[rr * 256 + c] : 0.f;
        v = (v > tmin && v <= tmax) ? 1.f : 0.f;
        mr[i][c + 4] = v;
    }
    if (tid < 128) { int i = tid >> 3, p = tid & 7; mr[i][p < 4 ? p : 256 + p] = 0.f; }
    __syncthreads();
    {
        int r = tid >> 4, x0 = (tid & 15) * 16;
        float w[24];
#pragma unroll
        for (int k = 0; k < 6; ++k) {
            float4 q = *(const float4*)&mr[r][x0 + 4 * k];
            w[4 * k] = q.x; w[4 * k + 1] = q.y; w[4 * k + 2] = q.z; w[4 * k + 3] = q.w;
        }
        float o[16];
        float s = 0.f;
#pragma unroll
        for (int k = 0; k < 9; ++k) s += w[k];
#pragma unroll
        for (int j = 0; j < 16; ++j) {
            o[j] = s * (1.f / 9.f);
            if (j < 15) s += w[j + 9] - w[j];
        }
#pragma unroll
        for (int k = 0; k < 4; ++k) {
            float4 q = {o[4 * k], o[4 * k + 1], o[4 * k + 2], o[4 * k + 3]};
            *(float4*)&hh[r][x0 + 4 * k] = q;
        }
    }
    __syncthreads();
    {
        int c = tid;
        float ld[16];
#pragma unroll
        for (int i = 0; i < 16; ++i) ld[i] = hh[i][c];
        float s = 0.f;
#pragma unroll
        for (int k = 0; k < 9; ++k) s += ld[k];
        float* dst = outp + (((size_t)plane) << 16);
#pragma unroll
        for (int j = 0; j < 8; ++j) {
            dst[(r0 + j) * 256 + c] = s * (1.f / 9.f);
            if (j < 7) s += ld[j + 9] - ld[j];
        }
    }
}

// ---- P2: fused pass2 (h+v) + pass3 (h_s2+v_s2) + minmax ----
__global__ __launch_bounds__(256) void k_hv2s2(const float* __restrict__ in,
                                               float* __restrict__ outp,
                                               unsigned* __restrict__ mnb,
                                               unsigned* __restrict__ mxb) {
    int plane = blockIdx.y;
    int r0 = blockIdx.x * 8;
    __shared__ float mr[31][264];
    __shared__ float hh[31][256];
    int tid = threadIdx.x;
    const float* src = in + (((size_t)plane) << 16);
    for (int l = tid; l < 31 * 264; l += 256) {
        int i = l / 264, c = l - i * 264;
        int rr = 2 * r0 - 8 + i, cc = c - 4;
        mr[i][c] = ((unsigned)rr < 256u && (unsigned)cc < 256u) ? src[rr * 256 + cc] : 0.f;
    }
    __syncthreads();
    for (int l = tid; l < 31 * 256; l += 256) {
        int i = l >> 8, x = l & 255;
        float s = 0.f;
#pragma unroll
        for (int k = 0; k < 9; ++k) s += mr[i][x + k];
        hh[i][x] = s * (1.f / 9.f);
    }
    __syncthreads();
    for (int l = tid; l < 23 * 256; l += 256) {
        int i2 = l >> 8, x = l & 255;
        float s = 0.f;
#pragma unroll
        for (int k = 0; k < 9; ++k) s += hh[i2 + k][x];
        float v = s * (1.f / 9.f);
        if ((unsigned)(2 * r0 - 4 + i2) >= 256u) v = 0.f;
        mr[i2][x + 4] = v;
    }
    if (tid < 184) { int i2 = tid / 8, p = tid & 7; mr[i2][p < 4 ? p : 256 + p] = 0.f; }
    __syncthreads();
    for (int l = tid; l < 23 * 128; l += 256) {
        int i2 = l >> 7, ox = l & 127;
        float s = 0.f;
#pragma unroll
        for (int k = 0; k < 9; ++k) s += mr[i2][2 * ox + k];
        hh[i2][ox] = s * (1.f / 9.f);
    }
    __syncthreads();
    float vmn = 1e30f, vmx = -1e30f;
    float* dst = outp + (size_t)plane * 16384;
#pragma unroll
    for (int q = 0; q < 4; ++q) {
        int l = tid + 256 * q;
        int jj = l >> 7, ox = l & 127;
        float s = 0.f;
#pragma unroll
        for (int k = 0; k < 9; ++k) s += hh[2 * jj + k][ox];
        s *= (1.f / 9.f);
        dst[(r0 + jj) * 128 + ox] = s;
        vmn = fminf(vmn, s); vmx = fmaxf(vmx, s);
    }
    __syncthreads();
    float* smn = &hh[23][0];
    float* smx = &hh[24][0];
    smn[tid] = vmn; smx[tid] = vmx; __syncthreads();
    for (int off = 128; off > 0; off >>= 1) {
        if (tid < off) {
            smn[tid] = fminf(smn[tid], smn[tid + off]);
            smx[tid] = fmaxf(smx[tid], smx[tid + off]);
        }
        __syncthreads();
    }
    if (tid == 0) {
        atomicMin(&mnb[plane], __float_as_uint(smn[0]));
        atomicMax(&mxb[plane], __float_as_uint(smx[0]));
    }
}

// ---- H2: r9-exact structure: 512 threads, output-split (grp = o-half), LDS-shared
//      stencil (one item/thread), 2 ch/iter, 2 barriers/iter, acc[8][4]=32 VGPR.
//      Norm folded at tile==64 (early return, touches no main-path state). ----
__global__ __launch_bounds__(512, 2) void k_hge(const float* __restrict__ feat,
                                                const float* __restrict__ At,
                                                const float* __restrict__ fcb,
                                                const float* __restrict__ p2,
                                                const unsigned* __restrict__ mnb,
                                                const unsigned* __restrict__ mxb,
                                                float* __restrict__ gdm,
                                                float* __restrict__ out) {
    int tile = blockIdx.x, b = blockIdx.y;
    int tid = threadIdx.x;
    if (tile == 64) {
        int base = b * 512 + tid;
#pragma unroll
        for (int q = 0; q < 40; ++q) {
            int i4 = base + 4096 * q;
            int idx = i4 * 4;
            int plane = idx >> 14;
            float mn = __uint_as_float(mnb[plane]), mx = __uint_as_float(mxb[plane]);
            float inv = 1.f / (mx - mn);
            float4 v = *(const float4*)&p2[idx];
            float4 o = {(v.x - mn) * inv, (v.y - mn) * inv, (v.z - mn) * inv, (v.w - mn) * inv};
            *(float4*)&gdm[idx] = o;
        }
        return;
    }
    int ty = (tile >> 3) * 16, tx = (tile & 7) * 16;
    int grp = tid >> 8, tg = tid & 255;     // grp: output half (o = grp*32 + ...)
    __shared__ float ft[2][20][21];         // [ch][r][c]        3360 B (single buf)
    __shared__ float tl[2][5][256];         // [ch][d][px]      10240 B (single buf; barrier-safe)
    __shared__ float al[2][2][5][64];       // [buf][ch][d][o]  10240 B (double buf)
    int og = tg >> 5, pg = tg & 31;
    float acc[8][4];                        // [pj][oi], px = pg + 32*pj, o = grp*32 + og*4 + oi
#pragma unroll
    for (int i = 0; i < 8; ++i)
#pragma unroll
        for (int j = 0; j < 4; ++j) acc[i][j] = 0.f;

    // staging: 800 ft (2ch x 20x20) + 640 al (2ch x 5 x 64o) = 1440 items over 512 threads
    const float* cur[3];
    int str3[3];
    bool ok[3];
#pragma unroll
    for (int j = 0; j < 3; ++j) {
        int l = tid + 512 * j;
        cur[j] = nullptr; str3[j] = 0; ok[j] = false;
        if (l < 800) {
            int ch = (l >= 400); int rem = l - ch * 400;
            int r = rem / 20, cx = rem - r * 20;
            int gy = ty - 2 + r, gx = tx - 2 + cx;
            if ((unsigned)gy < 128u && (unsigned)gx < 128u) {
                cur[j] = feat + (((size_t)(b * 64 + ch)) << 14) + gy * 128 + gx;
                str3[j] = 2 << 14;            // +2 channels per iteration
                ok[j] = true;
            }
        } else if (l < 1440) {
            int q = l - 800;
            int ch = (q >= 320); int k = q - ch * 320;   // k = d*64+o
            cur[j] = At + (k >> 6) * 4096 + ch * 64 + (k & 63);  // (d*64+c)*64+o, c=ch
            str3[j] = 128;                    // c += 2
            ok[j] = true;
        }
    }
    float pr[3];
#pragma unroll
    for (int j = 0; j < 3; ++j) pr[j] = ok[j] ? *cur[j] : 0.f;

    for (int g = 0; g < 32; ++g) {
        int buf = g & 1;
#pragma unroll
        for (int j = 0; j < 3; ++j) {
            int l = tid + 512 * j;
            if (l < 800) {
                int ch = (l >= 400); int rem = l - ch * 400;
                int r = rem / 20, cx = rem - r * 20;
                ft[ch][r][cx] = pr[j];
            } else if (l < 1440) {
                ((float*)al[buf])[l - 800] = pr[j];
            }
        }
        __syncthreads();
        if (g < 31) {
#pragma unroll
            for (int j = 0; j < 3; ++j) {
                if (ok[j]) { cur[j] += str3[j]; pr[j] = *cur[j]; }
            }
        }
        // stencil: each of 512 threads does ONE item (px = tg, ch = grp)
        {
            int cy = (tg >> 4) + 2, cx = (tg & 15) + 2;
            int ch = grp;
            float fm2 = ft[ch][cy - 2][cx], f2p = ft[ch][cy + 2][cx];
            float fl2 = ft[ch][cy][cx - 2], fr2 = ft[ch][cy][cx + 2];
            float a  = ft[ch][cy - 1][cx - 1], bq = ft[ch][cy - 1][cx], cc = ft[ch][cy - 1][cx + 1];
            float dd = ft[ch][cy][cx - 1],     ee = ft[ch][cy][cx],     ffv = ft[ch][cy][cx + 1];
            float g_ = ft[ch][cy + 1][cx - 1], h  = ft[ch][cy + 1][cx], i2 = ft[ch][cy + 1][cx + 1];
            tl[ch][0][tg] = (a + 2.f * bq + cc) - (g_ + 2.f * h + i2);
            tl[ch][1][tg] = 2.f * a + bq + dd - ffv - h - 2.f * i2;
            tl[ch][2][tg] = (a - cc) + 2.f * (dd - ffv) + (g_ - i2);
            tl[ch][3][tg] = -bq - 2.f * cc + dd - ffv + 2.f * g_ + h;
            tl[ch][4][tg] = ee - 0.125f * (bq + dd + ffv + h)
                          - 0.0625f * (fm2 + a + cc + fl2 + fr2 + g_ + i2 + f2p);
        }
        __syncthreads();
        // FMA: 8 px (pg+32*pj) x 4 outs (grp*32 + og*4 + oi)
#pragma unroll
        for (int ch = 0; ch < 2; ++ch) {
#pragma unroll
            for (int d = 0; d < 5; ++d) {
                float4 a0 = *(const float4*)&al[buf][ch][d][grp * 32 + og * 4];
                float av[4] = {a0.x, a0.y, a0.z, a0.w};
#pragma unroll
                for (int pj = 0; pj < 8; ++pj) {
                    float tv = tl[ch][d][pg + 32 * pj];
#pragma unroll
                    for (int oi = 0; oi < 4; ++oi)
                        acc[pj][oi] = fmaf(av[oi], tv, acc[pj][oi]);
                }
            }
        }
    }
    // epilogue: plain stores, each thread owns its (o, px) set
#pragma unroll
    for (int oi = 0; oi < 4; ++oi) {
        int o = grp * 32 + og * 4 + oi;
        float bias = fcb[o];
        float* dsto = out + (((size_t)(b * 64 + o)) << 14);
#pragma unroll
        for (int pj = 0; pj < 8; ++pj) {
            int pxl = pg + 32 * pj;
            dsto[(ty + (pxl >> 4)) * 128 + tx + (pxl & 15)] = acc[pj][oi] + bias;
        }
    }
}

extern "C" void kernel_launch(void* const* d_in, const int* in_sizes, int n_in,
                              void* d_out, int out_size, void* d_ws, size_t ws_size,
                              hipStream_t stream) {
    const float* x    = (const float*)d_in[0];
    const float* gdmw = (const float*)d_in[1];
    const float* convw= (const float*)d_in[2];
    const float* bng  = (const float*)d_in[3];
    const float* bnb  = (const float*)d_in[4];
    const float* bnm  = (const float*)d_in[5];
    const float* bnv  = (const float*)d_in[6];
    const float* feat = (const float*)d_in[7];
    const float* hw   = (const float*)d_in[8];
    const float* fcw  = (const float*)d_in[9];
    const float* fcb  = (const float*)d_in[10];
    float* out = (float*)d_out;
    float* ws  = (float*)d_ws;

    float* At   = ws + WS_AT;
    float* ysum = ws + WS_YSUM;
    unsigned* xmax = (unsigned*)(ws + WS_XMAX);
    int* hist   = (int*)(ws + WS_HIST);
    unsigned* mnb = (unsigned*)(ws + WS_MN);
    unsigned* mxb = (unsigned*)(ws + WS_MX);
    float* xp   = ws + WS_XP;
    float* ia   = ws + WS_IA;
    float* xgl  = ws + WS_XGL;
    float* p2   = ws + WS_XP + 20480;

    float* hge = out + GDM_OUT;
    float* p0  = hge;                    // pool scratch in hge region (overwritten by k_hge)

    k_front  <<<2129, 256, 0, stream>>>(x, hw, fcw, xp, ia, At, ws + WS_YSUM, mnb, mxb);
    k_convgl <<<2560, 256, 0, stream>>>(xp, convw, ysum, ia, gdmw, xgl, hist, xmax);
    k_hv1    <<<dim3(32, 40), 256, 0, stream>>>(xgl, ysum, bng, bnb, bnm, bnv, hist, xmax, p0);
    k_hv2s2  <<<dim3(16, 40), 256, 0, stream>>>(p0, p2, mnb, mxb);
    k_hge    <<<dim3(65, 8), 512, 0, stream>>>(feat, At, fcb, p2, mnb, mxb, out, hge);
}

// Round 13
// 251.519 us; speedup vs baseline: 1.2133x; 1.0185x over previous
//
#include <hip/hip_runtime.h>
#include <hip/hip_bf16.h>
#include <math.h>

// ---------------- workspace layout (floats) ----------------
#define WS_AT    0            // At fp32 20480 (dedicated)
#define WS_YSUM  20480        // 40
#define WS_XMAX  20520        // 8
#define WS_HIST  20528        // 816 (int)
#define WS_MN    21376        // 40 (uint)
#define WS_MX    21440        // 40 (uint)
#define WS_XP    21504        // 8*3*256*256 = 1572864
#define WS_IA    1594368      // 8*256*256   = 524288
#define WS_XGL   2118656      // 8*256*256   = 524288
// P2 = ws + WS_XP + 20480 (1310720 floats, inside xp region, written after convgl)

#define GDM_OUT  655360       // 8*5*128*128

static __device__ __forceinline__ float xv_val(int i) {
    double t = (double)i / 100.0;
    return (float)(10.0 * t * t * t);
}

// ---- F1: fused [pool3+mean | mixA | zero/init accumulators] ----
__global__ __launch_bounds__(256) void k_front(const float* __restrict__ x,
                                               const float* __restrict__ hw,
                                               const float* __restrict__ fcw,
                                               float* __restrict__ xp,
                                               float* __restrict__ ia,
                                               float* __restrict__ At,
                                               float* __restrict__ zr,
                                               unsigned* __restrict__ mnb,
                                               unsigned* __restrict__ mxb) {
    int bid = blockIdx.x;
    if (bid < 2048) {
        int idx = bid * 256 + threadIdx.x;
        int b = idx >> 16; int p = idx & 65535; int oy = p >> 8; int ox = p & 255;
        float cs[3];
#pragma unroll
        for (int c = 0; c < 3; ++c) {
            const float* src = x + (((size_t)(b * 3 + c)) << 18);
            float s = 0.f;
#pragma unroll
            for (int dy = -1; dy <= 1; ++dy) {
                int iy = 2 * oy + dy; if ((unsigned)iy >= 512u) continue;
#pragma unroll
                for (int dx = -1; dx <= 1; ++dx) {
                    int ix = 2 * ox + dx; if ((unsigned)ix >= 512u) continue;
                    s += src[iy * 512 + ix];
                }
            }
            cs[c] = s * (1.f / 9.f);
            xp[(((size_t)(b * 3 + c)) << 16) + p] = cs[c];
        }
        ia[(((size_t)b) << 16) + p] = (cs[0] + cs[1] + cs[2]) * (1.f / 3.f);
    } else if (bid < 2128) {
        int idx = (bid - 2048) * 256 + threadIdx.x;   // 20480
        int o = idx & 63; int k = idx >> 6;           // k = d*64+c
        int d = k >> 6; int c = k & 63;
        const int goff[5] = {0, 1, 2, 3, 8};
        float s = 0.f;
        for (int m = 0; m < 64; ++m)
            s += fcw[o * 320 + d * 64 + m] * hw[(m * 64 + c) * 9 + goff[d]];
        At[k * 64 + o] = s * ((d == 4) ? 4.f : 1.f);
    } else {
#pragma unroll
        for (int q = 0; q < 4; ++q) {
            int i = threadIdx.x + 256 * q;
            if (i < 864) zr[i] = 0.f;
        }
        if (threadIdx.x < 40) mnb[threadIdx.x] = 0x7f7fffffu;
        else if (threadIdx.x < 80) mxb[threadIdx.x - 40] = 0u;
    }
}

// ---- G2+G4 merged: conv7 spatial-sum (512 blocks) | x_GL+hist+max (2048 blocks) ----
__global__ __launch_bounds__(256) void k_convgl(const float* __restrict__ xp,
                                                const float* __restrict__ w,
                                                float* __restrict__ ysum,
                                                const float* __restrict__ ia,
                                                const float* __restrict__ gdmw,
                                                float* __restrict__ xgl,
                                                int* __restrict__ hist,
                                                unsigned* __restrict__ xmax) {
    __shared__ float wsm[735];
    __shared__ float red[256];
    __shared__ float xv[101];
    __shared__ int sh[102];
    int bid = blockIdx.x;
    int tid = threadIdx.x;
    if (bid < 512) {
        int b = bid >> 6;
        int p = (bid & 63) * 256 + tid;
        int oy = p >> 7, ox = p & 127;
        for (int l = tid; l < 735; l += 256) wsm[l] = w[l];
        __syncthreads();
        float s[5] = {0.f, 0.f, 0.f, 0.f, 0.f};
        for (int ic = 0; ic < 3; ++ic) {
            const float* src = xp + (((size_t)(b * 3 + ic)) << 16);
#pragma unroll
            for (int r = 0; r < 7; ++r) {
                int iy = 2 * oy - 3 + r; if ((unsigned)iy >= 256u) continue;
#pragma unroll
                for (int ss = 0; ss < 7; ++ss) {
                    int ix = 2 * ox - 3 + ss; if ((unsigned)ix >= 256u) continue;
                    float v = src[iy * 256 + ix];
                    int wi = (ic * 7 + r) * 7 + ss;
#pragma unroll
                    for (int co = 0; co < 5; ++co) s[co] = fmaf(wsm[co * 147 + wi], v, s[co]);
                }
            }
        }
#pragma unroll
        for (int co = 0; co < 5; ++co) {
            red[tid] = s[co]; __syncthreads();
            for (int off = 128; off > 0; off >>= 1) {
                if (tid < off) red[tid] += red[tid + off];
                __syncthreads();
            }
            if (tid == 0) atomicAdd(&ysum[b * 5 + co], red[0]);
            __syncthreads();
        }
    } else {
        int idx = bid - 512;
        int b = idx >> 8;
        int p = (idx & 255) * 256 + tid;
        int y = p >> 8, x = p & 255;
        if (tid < 101) xv[tid] = xv_val(tid);
        if (tid < 102) sh[tid] = 0;
        __syncthreads();
        const float* src = ia + (((size_t)b) << 16);
        float a1 = gdmw[0] * 4.f;
        auto rd = [&](int dy, int dx) -> float {
            int iy = y + dy, ix = x + dx;
            if ((unsigned)iy >= 256u || (unsigned)ix >= 256u) return 0.f;
            return src[iy * 256 + ix];
        };
        float acc = rd(0, 0)
            - 0.125f  * (rd(-1, 0) + rd(0, -1) + rd(0, 1) + rd(1, 0))
            - 0.0625f * (rd(-2, 0) + rd(-1, -1) + rd(-1, 1) + rd(0, -2) +
                         rd(0, 2) + rd(1, -1) + rd(1, 1) + rd(2, 0));
        float raw = fabsf(a1 * acc);
        float val = (raw < 1e-6f) ? 0.f : raw;
        xgl[(((size_t)b) << 16) + p] = val;
        if (val > 0.f) {
            int lo = 0, hi = 101;
            while (lo < hi) { int mid = (lo + hi) >> 1; if (val <= xv[mid]) hi = mid; else lo = mid + 1; }
            atomicAdd(&sh[lo], 1);
        }
        red[tid] = val; __syncthreads();
        for (int off = 128; off > 0; off >>= 1) {
            if (tid < off) red[tid] = fmaxf(red[tid], red[tid + off]);
            __syncthreads();
        }
        if (tid == 0) atomicMax(&xmax[b], __float_as_uint(red[0]));
        if (tid < 102 && sh[tid]) atomicAdd(&hist[b * 102 + tid], sh[tid]);
    }
}

// ---- P1: inline thresholds + mask + h-box9 + v-box9 -> p0 [40][256][256] ----
#define F1_STR 268
__global__ __launch_bounds__(256) void k_hv1(const float* __restrict__ in,
                                             const float* __restrict__ ysum,
                                             const float* __restrict__ gamma,
                                             const float* __restrict__ beta,
                                             const float* __restrict__ mean,
                                             const float* __restrict__ var,
                                             const int* __restrict__ hist,
                                             const unsigned* __restrict__ xmax,
                                             float* __restrict__ outp) {
    int plane = blockIdx.y;
    int r0 = blockIdx.x * 8;
    int b = plane / 5, band = plane - 5 * b;
    __shared__ float sthr[4];
    int tid = threadIdx.x;
    if (tid == 0) {
        float wa[5];
        for (int c = 1; c < 5; ++c) {
            float m = ysum[b * 5 + c] * (1.f / 16384.f);
            wa[c] = tanhf((m - mean[c]) * rsqrtf(var[c] + 1e-5f) * gamma[c] + beta[c]);
        }
        float pr[4] = {0.2f + 0.05f * wa[1], 0.4f + 0.05f * wa[2],
                       0.6f + 0.05f * wa[3], 0.8f + 0.05f * wa[4]};
        auto sw = [&](int i, int j) { if (pr[i] > pr[j]) { float t = pr[i]; pr[i] = pr[j]; pr[j] = t; } };
        sw(0, 1); sw(2, 3); sw(0, 2); sw(1, 3); sw(1, 2);
        int all = 0;
        for (int i = 0; i <= 101; ++i) all += hist[b * 102 + i];
        float bestz[4] = {1e30f, 1e30f, 1e30f, 1e30f};
        int besti[4] = {0, 0, 0, 0};
        int cum = 0;
        for (int i = 0; i <= 100; ++i) {
            cum += hist[b * 102 + i];
            float pct = (float)cum / (float)all;
            for (int t = 0; t < 4; ++t) {
                float z = fabsf(pct - pr[t]);
                if (z < bestz[t]) { bestz[t] = z; besti[t] = i; }
            }
        }
        for (int t = 0; t < 4; ++t) sthr[t] = xv_val(besti[t]);
    }
    __syncthreads();
    float tmin = (band == 0) ? 0.f : sthr[band - 1];
    float tmax = (band == 4) ? __uint_as_float(xmax[b]) : sthr[band];
    const float* src = in + (((size_t)b) << 16);
    __shared__ float mr[16][F1_STR];
    __shared__ float hh[16][256];
    for (int l = tid; l < 16 * 256; l += 256) {
        int i = l >> 8, c = l & 255;
        int rr = r0 - 4 + i;
        float v = ((unsigned)rr < 256u) ? src[rr * 256 + c] : 0.f;
        v = (v > tmin && v <= tmax) ? 1.f : 0.f;
        mr[i][c + 4] = v;
    }
    if (tid < 128) { int i = tid >> 3, p = tid & 7; mr[i][p < 4 ? p : 256 + p] = 0.f; }
    __syncthreads();
    {
        int r = tid >> 4, x0 = (tid & 15) * 16;
        float w[24];
#pragma unroll
        for (int k = 0; k < 6; ++k) {
            float4 q = *(const float4*)&mr[r][x0 + 4 * k];
            w[4 * k] = q.x; w[4 * k + 1] = q.y; w[4 * k + 2] = q.z; w[4 * k + 3] = q.w;
        }
        float o[16];
        float s = 0.f;
#pragma unroll
        for (int k = 0; k < 9; ++k) s += w[k];
#pragma unroll
        for (int j = 0; j < 16; ++j) {
            o[j] = s * (1.f / 9.f);
            if (j < 15) s += w[j + 9] - w[j];
        }
#pragma unroll
        for (int k = 0; k < 4; ++k) {
            float4 q = {o[4 * k], o[4 * k + 1], o[4 * k + 2], o[4 * k + 3]};
            *(float4*)&hh[r][x0 + 4 * k] = q;
        }
    }
    __syncthreads();
    {
        int c = tid;
        float ld[16];
#pragma unroll
        for (int i = 0; i < 16; ++i) ld[i] = hh[i][c];
        float s = 0.f;
#pragma unroll
        for (int k = 0; k < 9; ++k) s += ld[k];
        float* dst = outp + (((size_t)plane) << 16);
#pragma unroll
        for (int j = 0; j < 8; ++j) {
            dst[(r0 + j) * 256 + c] = s * (1.f / 9.f);
            if (j < 7) s += ld[j + 9] - ld[j];
        }
    }
}

// ---- P2: fused pass2 (h+v) + pass3 (h_s2+v_s2) + minmax ----
__global__ __launch_bounds__(256) void k_hv2s2(const float* __restrict__ in,
                                               float* __restrict__ outp,
                                               unsigned* __restrict__ mnb,
                                               unsigned* __restrict__ mxb) {
    int plane = blockIdx.y;
    int r0 = blockIdx.x * 8;
    __shared__ float mr[31][264];
    __shared__ float hh[31][256];
    int tid = threadIdx.x;
    const float* src = in + (((size_t)plane) << 16);
    for (int l = tid; l < 31 * 264; l += 256) {
        int i = l / 264, c = l - i * 264;
        int rr = 2 * r0 - 8 + i, cc = c - 4;
        mr[i][c] = ((unsigned)rr < 256u && (unsigned)cc < 256u) ? src[rr * 256 + cc] : 0.f;
    }
    __syncthreads();
    for (int l = tid; l < 31 * 256; l += 256) {
        int i = l >> 8, x = l & 255;
        float s = 0.f;
#pragma unroll
        for (int k = 0; k < 9; ++k) s += mr[i][x + k];
        hh[i][x] = s * (1.f / 9.f);
    }
    __syncthreads();
    for (int l = tid; l < 23 * 256; l += 256) {
        int i2 = l >> 8, x = l & 255;
        float s = 0.f;
#pragma unroll
        for (int k = 0; k < 9; ++k) s += hh[i2 + k][x];
        float v = s * (1.f / 9.f);
        if ((unsigned)(2 * r0 - 4 + i2) >= 256u) v = 0.f;
        mr[i2][x + 4] = v;
    }
    if (tid < 184) { int i2 = tid / 8, p = tid & 7; mr[i2][p < 4 ? p : 256 + p] = 0.f; }
    __syncthreads();
    for (int l = tid; l < 23 * 128; l += 256) {
        int i2 = l >> 7, ox = l & 127;
        float s = 0.f;
#pragma unroll
        for (int k = 0; k < 9; ++k) s += mr[i2][2 * ox + k];
        hh[i2][ox] = s * (1.f / 9.f);
    }
    __syncthreads();
    float vmn = 1e30f, vmx = -1e30f;
    float* dst = outp + (size_t)plane * 16384;
#pragma unroll
    for (int q = 0; q < 4; ++q) {
        int l = tid + 256 * q;
        int jj = l >> 7, ox = l & 127;
        float s = 0.f;
#pragma unroll
        for (int k = 0; k < 9; ++k) s += hh[2 * jj + k][ox];
        s *= (1.f / 9.f);
        dst[(r0 + jj) * 128 + ox] = s;
        vmn = fminf(vmn, s); vmx = fmaxf(vmx, s);
    }
    __syncthreads();
    float* smn = &hh[23][0];
    float* smx = &hh[24][0];
    smn[tid] = vmn; smx[tid] = vmx; __syncthreads();
    for (int off = 128; off > 0; off >>= 1) {
        if (tid < off) {
            smn[tid] = fminf(smn[tid], smn[tid + off]);
            smx[tid] = fmaxf(smx[tid], smx[tid + off]);
        }
        __syncthreads();
    }
    if (tid == 0) {
        atomicMin(&mnb[plane], __float_as_uint(smn[0]));
        atomicMax(&mxb[plane], __float_as_uint(smx[0]));
    }
}

// ---- H2: r9 skeleton (512 thr, output-split, LDS-shared stencil, 2 ch/iter,
//      2 barriers/iter) with FMA remapped to 4px x 8o per thread:
//      tv = tl[ch][d][(tg&63)+64*pj] (lane-stride-1, conflict-free),
//      av = 2 x b128 wave-uniform broadcast. LDS issues/iter 90 -> 60. ----
__global__ __launch_bounds__(512, 2) void k_hge(const float* __restrict__ feat,
                                                const float* __restrict__ At,
                                                const float* __restrict__ fcb,
                                                const float* __restrict__ p2,
                                                const unsigned* __restrict__ mnb,
                                                const unsigned* __restrict__ mxb,
                                                float* __restrict__ gdm,
                                                float* __restrict__ out) {
    int tile = blockIdx.x, b = blockIdx.y;
    int tid = threadIdx.x;
    if (tile == 64) {
        int base = b * 512 + tid;
#pragma unroll
        for (int q = 0; q < 40; ++q) {
            int i4 = base + 4096 * q;
            int idx = i4 * 4;
            int plane = idx >> 14;
            float mn = __uint_as_float(mnb[plane]), mx = __uint_as_float(mxb[plane]);
            float inv = 1.f / (mx - mn);
            float4 v = *(const float4*)&p2[idx];
            float4 o = {(v.x - mn) * inv, (v.y - mn) * inv, (v.z - mn) * inv, (v.w - mn) * inv};
            *(float4*)&gdm[idx] = o;
        }
        return;
    }
    int ty = (tile >> 3) * 16, tx = (tile & 7) * 16;
    int grp = tid >> 8, tg = tid & 255;     // grp: output half (o = grp*32 + ...)
    __shared__ float ft[2][20][21];         // [ch][r][c]        3360 B (single buf)
    __shared__ float tl[2][5][256];         // [ch][d][px]      10240 B (single buf; barrier-safe)
    __shared__ float al[2][2][5][64];       // [buf][ch][d][o]  10240 B (double buf)
    int og = tg >> 6;                       // 0..3: o-octet within half
    int pl = tg & 63;                       // lane px base
    float acc[4][8];                        // [pj][oi], px = pl + 64*pj, o = grp*32 + og*8 + oi
#pragma unroll
    for (int i = 0; i < 4; ++i)
#pragma unroll
        for (int j = 0; j < 8; ++j) acc[i][j] = 0.f;

    // staging: 800 ft (2ch x 20x20) + 640 al (2ch x 5 x 64o) = 1440 items over 512 threads
    const float* cur[3];
    int str3[3];
    bool ok[3];
#pragma unroll
    for (int j = 0; j < 3; ++j) {
        int l = tid + 512 * j;
        cur[j] = nullptr; str3[j] = 0; ok[j] = false;
        if (l < 800) {
            int ch = (l >= 400); int rem = l - ch * 400;
            int r = rem / 20, cx = rem - r * 20;
            int gy = ty - 2 + r, gx = tx - 2 + cx;
            if ((unsigned)gy < 128u && (unsigned)gx < 128u) {
                cur[j] = feat + (((size_t)(b * 64 + ch)) << 14) + gy * 128 + gx;
                str3[j] = 2 << 14;            // +2 channels per iteration
                ok[j] = true;
            }
        } else if (l < 1440) {
            int q = l - 800;
            int ch = (q >= 320); int k = q - ch * 320;   // k = d*64+o
            cur[j] = At + (k >> 6) * 4096 + ch * 64 + (k & 63);  // (d*64+c)*64+o, c=ch
            str3[j] = 128;                    // c += 2
            ok[j] = true;
        }
    }
    float pr[3];
#pragma unroll
    for (int j = 0; j < 3; ++j) pr[j] = ok[j] ? *cur[j] : 0.f;

    for (int g = 0; g < 32; ++g) {
        int buf = g & 1;
#pragma unroll
        for (int j = 0; j < 3; ++j) {
            int l = tid + 512 * j;
            if (l < 800) {
                int ch = (l >= 400); int rem = l - ch * 400;
                int r = rem / 20, cx = rem - r * 20;
                ft[ch][r][cx] = pr[j];
            } else if (l < 1440) {
                ((float*)al[buf])[l - 800] = pr[j];
            }
        }
        __syncthreads();
        if (g < 31) {
#pragma unroll
            for (int j = 0; j < 3; ++j) {
                if (ok[j]) { cur[j] += str3[j]; pr[j] = *cur[j]; }
            }
        }
        // stencil: each of 512 threads does ONE item (px = tg, ch = grp)
        {
            int cy = (tg >> 4) + 2, cx = (tg & 15) + 2;
            int ch = grp;
            float fm2 = ft[ch][cy - 2][cx], f2p = ft[ch][cy + 2][cx];
            float fl2 = ft[ch][cy][cx - 2], fr2 = ft[ch][cy][cx + 2];
            float a  = ft[ch][cy - 1][cx - 1], bq = ft[ch][cy - 1][cx], cc = ft[ch][cy - 1][cx + 1];
            float dd = ft[ch][cy][cx - 1],     ee = ft[ch][cy][cx],     ffv = ft[ch][cy][cx + 1];
            float g_ = ft[ch][cy + 1][cx - 1], h  = ft[ch][cy + 1][cx], i2 = ft[ch][cy + 1][cx + 1];
            tl[ch][0][tg] = (a + 2.f * bq + cc) - (g_ + 2.f * h + i2);
            tl[ch][1][tg] = 2.f * a + bq + dd - ffv - h - 2.f * i2;
            tl[ch][2][tg] = (a - cc) + 2.f * (dd - ffv) + (g_ - i2);
            tl[ch][3][tg] = -bq - 2.f * cc + dd - ffv + 2.f * g_ + h;
            tl[ch][4][tg] = ee - 0.125f * (bq + dd + ffv + h)
                          - 0.0625f * (fm2 + a + cc + fl2 + fr2 + g_ + i2 + f2p);
        }
        __syncthreads();
        // FMA: 4 px (pl + 64*pj) x 8 outs (grp*32 + og*8 + oi)
#pragma unroll
        for (int ch = 0; ch < 2; ++ch) {
#pragma unroll
            for (int d = 0; d < 5; ++d) {
                float4 a0 = *(const float4*)&al[buf][ch][d][grp * 32 + og * 8];
                float4 a1 = *(const float4*)&al[buf][ch][d][grp * 32 + og * 8 + 4];
                float av[8] = {a0.x, a0.y, a0.z, a0.w, a1.x, a1.y, a1.z, a1.w};
#pragma unroll
                for (int pj = 0; pj < 4; ++pj) {
                    float tv = tl[ch][d][pl + 64 * pj];
#pragma unroll
                    for (int oi = 0; oi < 8; ++oi)
                        acc[pj][oi] = fmaf(av[oi], tv, acc[pj][oi]);
                }
            }
        }
    }
    // epilogue: plain stores, each thread owns 8 outs x 4 px
#pragma unroll
    for (int oi = 0; oi < 8; ++oi) {
        int o = grp * 32 + og * 8 + oi;
        float bias = fcb[o];
        float* dsto = out + (((size_t)(b * 64 + o)) << 14);
#pragma unroll
        for (int pj = 0; pj < 4; ++pj) {
            int pxl = pl + 64 * pj;
            dsto[(ty + (pxl >> 4)) * 128 + tx + (pxl & 15)] = acc[pj][oi] + bias;
        }
    }
}

extern "C" void kernel_launch(void* const* d_in, const int* in_sizes, int n_in,
                              void* d_out, int out_size, void* d_ws, size_t ws_size,
                              hipStream_t stream) {
    const float* x    = (const float*)d_in[0];
    const float* gdmw = (const float*)d_in[1];
    const float* convw= (const float*)d_in[2];
    const float* bng  = (const float*)d_in[3];
    const float* bnb  = (const float*)d_in[4];
    const float* bnm  = (const float*)d_in[5];
    const float* bnv  = (const float*)d_in[6];
    const float* feat = (const float*)d_in[7];
    const float* hw   = (const float*)d_in[8];
    const float* fcw  = (const float*)d_in[9];
    const float* fcb  = (const float*)d_in[10];
    float* out = (float*)d_out;
    float* ws  = (float*)d_ws;

    float* At   = ws + WS_AT;
    float* ysum = ws + WS_YSUM;
    unsigned* xmax = (unsigned*)(ws + WS_XMAX);
    int* hist   = (int*)(ws + WS_HIST);
    unsigned* mnb = (unsigned*)(ws + WS_MN);
    unsigned* mxb = (unsigned*)(ws + WS_MX);
    float* xp   = ws + WS_XP;
    float* ia   = ws + WS_IA;
    float* xgl  = ws + WS_XGL;
    float* p2   = ws + WS_XP + 20480;

    float* hge = out + GDM_OUT;
    float* p0  = hge;                    // pool scratch in hge region (overwritten by k_hge)

    k_front  <<<2129, 256, 0, stream>>>(x, hw, fcw, xp, ia, At, ws + WS_YSUM, mnb, mxb);
    k_convgl <<<2560, 256, 0, stream>>>(xp, convw, ysum, ia, gdmw, xgl, hist, xmax);
    k_hv1    <<<dim3(32, 40), 256, 0, stream>>>(xgl, ysum, bng, bnb, bnm, bnv, hist, xmax, p0);
    k_hv2s2  <<<dim3(16, 40), 256, 0, stream>>>(p0, p2, mnb, mxb);
    k_hge    <<<dim3(65, 8), 512, 0, stream>>>(feat, At, fcb, p2, mnb, mxb, out, hge);
}

// Round 14
// 242.084 us; speedup vs baseline: 1.2606x; 1.0390x over previous
//
#include <hip/hip_runtime.h>
#include <hip/hip_bf16.h>
#include <math.h>

// ---------------- workspace layout (floats) ----------------
#define WS_AT    0            // At fp32 20480 (dedicated)
#define WS_YSUM  20480        // 40
#define WS_XMAX  20520        // 8
#define WS_HIST  20528        // 816 (int)
#define WS_MN    21376        // 40 (uint)
#define WS_MX    21440        // 40 (uint)
#define WS_XP    21504        // 8*3*256*256 = 1572864
#define WS_IA    1594368      // 8*256*256   = 524288
#define WS_XGL   2118656      // 8*256*256   = 524288
// P2 = ws + WS_XP + 20480 (1310720 floats, inside xp region, written after convgl)

#define GDM_OUT  655360       // 8*5*128*128

static __device__ __forceinline__ float xv_val(int i) {
    double t = (double)i / 100.0;
    return (float)(10.0 * t * t * t);
}

// ---- F1: fused [pool3+mean | mixA | zero/init accumulators] ----
__global__ __launch_bounds__(256) void k_front(const float* __restrict__ x,
                                               const float* __restrict__ hw,
                                               const float* __restrict__ fcw,
                                               float* __restrict__ xp,
                                               float* __restrict__ ia,
                                               float* __restrict__ At,
                                               float* __restrict__ zr,
                                               unsigned* __restrict__ mnb,
                                               unsigned* __restrict__ mxb) {
    int bid = blockIdx.x;
    if (bid < 2048) {
        int idx = bid * 256 + threadIdx.x;
        int b = idx >> 16; int p = idx & 65535; int oy = p >> 8; int ox = p & 255;
        float cs[3];
#pragma unroll
        for (int c = 0; c < 3; ++c) {
            const float* src = x + (((size_t)(b * 3 + c)) << 18);
            float s = 0.f;
#pragma unroll
            for (int dy = -1; dy <= 1; ++dy) {
                int iy = 2 * oy + dy; if ((unsigned)iy >= 512u) continue;
#pragma unroll
                for (int dx = -1; dx <= 1; ++dx) {
                    int ix = 2 * ox + dx; if ((unsigned)ix >= 512u) continue;
                    s += src[iy * 512 + ix];
                }
            }
            cs[c] = s * (1.f / 9.f);
            xp[(((size_t)(b * 3 + c)) << 16) + p] = cs[c];
        }
        ia[(((size_t)b) << 16) + p] = (cs[0] + cs[1] + cs[2]) * (1.f / 3.f);
    } else if (bid < 2128) {
        int idx = (bid - 2048) * 256 + threadIdx.x;   // 20480
        int o = idx & 63; int k = idx >> 6;           // k = d*64+c
        int d = k >> 6; int c = k & 63;
        const int goff[5] = {0, 1, 2, 3, 8};
        float s = 0.f;
        for (int m = 0; m < 64; ++m)
            s += fcw[o * 320 + d * 64 + m] * hw[(m * 64 + c) * 9 + goff[d]];
        At[k * 64 + o] = s * ((d == 4) ? 4.f : 1.f);
    } else {
#pragma unroll
        for (int q = 0; q < 4; ++q) {
            int i = threadIdx.x + 256 * q;
            if (i < 864) zr[i] = 0.f;
        }
        if (threadIdx.x < 40) mnb[threadIdx.x] = 0x7f7fffffu;
        else if (threadIdx.x < 80) mxb[threadIdx.x - 40] = 0u;
    }
}

// ---- G2+G4 merged: conv7 spatial-sum (512 blocks) | x_GL+hist+max (2048 blocks) ----
__global__ __launch_bounds__(256) void k_convgl(const float* __restrict__ xp,
                                                const float* __restrict__ w,
                                                float* __restrict__ ysum,
                                                const float* __restrict__ ia,
                                                const float* __restrict__ gdmw,
                                                float* __restrict__ xgl,
                                                int* __restrict__ hist,
                                                unsigned* __restrict__ xmax) {
    __shared__ float wsm[735];
    __shared__ float red[256];
    __shared__ float xv[101];
    __shared__ int sh[102];
    int bid = blockIdx.x;
    int tid = threadIdx.x;
    if (bid < 512) {
        int b = bid >> 6;
        int p = (bid & 63) * 256 + tid;
        int oy = p >> 7, ox = p & 127;
        for (int l = tid; l < 735; l += 256) wsm[l] = w[l];
        __syncthreads();
        float s[5] = {0.f, 0.f, 0.f, 0.f, 0.f};
        for (int ic = 0; ic < 3; ++ic) {
            const float* src = xp + (((size_t)(b * 3 + ic)) << 16);
#pragma unroll
            for (int r = 0; r < 7; ++r) {
                int iy = 2 * oy - 3 + r; if ((unsigned)iy >= 256u) continue;
#pragma unroll
                for (int ss = 0; ss < 7; ++ss) {
                    int ix = 2 * ox - 3 + ss; if ((unsigned)ix >= 256u) continue;
                    float v = src[iy * 256 + ix];
                    int wi = (ic * 7 + r) * 7 + ss;
#pragma unroll
                    for (int co = 0; co < 5; ++co) s[co] = fmaf(wsm[co * 147 + wi], v, s[co]);
                }
            }
        }
#pragma unroll
        for (int co = 0; co < 5; ++co) {
            red[tid] = s[co]; __syncthreads();
            for (int off = 128; off > 0; off >>= 1) {
                if (tid < off) red[tid] += red[tid + off];
                __syncthreads();
            }
            if (tid == 0) atomicAdd(&ysum[b * 5 + co], red[0]);
            __syncthreads();
        }
    } else {
        int idx = bid - 512;
        int b = idx >> 8;
        int p = (idx & 255) * 256 + tid;
        int y = p >> 8, x = p & 255;
        if (tid < 101) xv[tid] = xv_val(tid);
        if (tid < 102) sh[tid] = 0;
        __syncthreads();
        const float* src = ia + (((size_t)b) << 16);
        float a1 = gdmw[0] * 4.f;
        auto rd = [&](int dy, int dx) -> float {
            int iy = y + dy, ix = x + dx;
            if ((unsigned)iy >= 256u || (unsigned)ix >= 256u) return 0.f;
            return src[iy * 256 + ix];
        };
        float acc = rd(0, 0)
            - 0.125f  * (rd(-1, 0) + rd(0, -1) + rd(0, 1) + rd(1, 0))
            - 0.0625f * (rd(-2, 0) + rd(-1, -1) + rd(-1, 1) + rd(0, -2) +
                         rd(0, 2) + rd(1, -1) + rd(1, 1) + rd(2, 0));
        float raw = fabsf(a1 * acc);
        float val = (raw < 1e-6f) ? 0.f : raw;
        xgl[(((size_t)b) << 16) + p] = val;
        if (val > 0.f) {
            int lo = 0, hi = 101;
            while (lo < hi) { int mid = (lo + hi) >> 1; if (val <= xv[mid]) hi = mid; else lo = mid + 1; }
            atomicAdd(&sh[lo], 1);
        }
        red[tid] = val; __syncthreads();
        for (int off = 128; off > 0; off >>= 1) {
            if (tid < off) red[tid] = fmaxf(red[tid], red[tid + off]);
            __syncthreads();
        }
        if (tid == 0) atomicMax(&xmax[b], __float_as_uint(red[0]));
        if (tid < 102 && sh[tid]) atomicAdd(&hist[b * 102 + tid], sh[tid]);
    }
}

// ---- P: fully fused thresholds + mask + pass1(h,v) + pass2(h,v) + pass3(h_s2,v_s2) + minmax
//      xgl -> p2 [40][128][128]. Halo: final rows r0..r0+7 <= pass2out abs 2r0-4..+18 (23)
//      <= P1 abs 2r0-8..+22 (31) <= P1h abs 2r0-12..+26 (39) <= mask rows 2r0-12..2r0+26. ----
__global__ __launch_bounds__(256) void k_pool(const float* __restrict__ xgl,
                                              const float* __restrict__ ysum,
                                              const float* __restrict__ gamma,
                                              const float* __restrict__ beta,
                                              const float* __restrict__ mean,
                                              const float* __restrict__ var,
                                              const int* __restrict__ hist,
                                              const unsigned* __restrict__ xmax,
                                              float* __restrict__ p2,
                                              unsigned* __restrict__ mnb,
                                              unsigned* __restrict__ mxb) {
    int plane = blockIdx.y;
    int r0 = blockIdx.x * 8;                 // final output rows r0..r0+7 (of 128)
    int b = plane / 5, band = plane - 5 * b;
    __shared__ float mk[39][264];            // mask rows abs 2r0-12+i, col+4 shift (41184 B)
    __shared__ float p1[31][264];            // P1 rows abs 2r0-8+pr, col+4 shift (32736 B)
    __shared__ float sthr[4];
    int tid = threadIdx.x;
    if (tid == 0) {
        float wa[5];
        for (int c = 1; c < 5; ++c) {
            float m = ysum[b * 5 + c] * (1.f / 16384.f);
            wa[c] = tanhf((m - mean[c]) * rsqrtf(var[c] + 1e-5f) * gamma[c] + beta[c]);
        }
        float pr_[4] = {0.2f + 0.05f * wa[1], 0.4f + 0.05f * wa[2],
                        0.6f + 0.05f * wa[3], 0.8f + 0.05f * wa[4]};
        auto sw = [&](int i, int j) { if (pr_[i] > pr_[j]) { float t = pr_[i]; pr_[i] = pr_[j]; pr_[j] = t; } };
        sw(0, 1); sw(2, 3); sw(0, 2); sw(1, 3); sw(1, 2);
        int all = 0;
        for (int i = 0; i <= 101; ++i) all += hist[b * 102 + i];
        float bestz[4] = {1e30f, 1e30f, 1e30f, 1e30f};
        int besti[4] = {0, 0, 0, 0};
        int cum = 0;
        for (int i = 0; i <= 100; ++i) {
            cum += hist[b * 102 + i];
            float pct = (float)cum / (float)all;
            for (int t = 0; t < 4; ++t) {
                float z = fabsf(pct - pr_[t]);
                if (z < bestz[t]) { bestz[t] = z; besti[t] = i; }
            }
        }
        for (int t = 0; t < 4; ++t) sthr[t] = xv_val(besti[t]);
    }
    __syncthreads();
    float tmin = (band == 0) ? 0.f : sthr[band - 1];
    float tmax = (band == 4) ? __uint_as_float(xmax[b]) : sthr[band];
    const float* src = xgl + (((size_t)b) << 16);
    // Phase A: stage mask 39 x 264 (zero-padded rows/cols)
    for (int l = tid; l < 39 * 264; l += 256) {
        int i = l / 264, c = l - i * 264;
        int rr = 2 * r0 - 12 + i, cc = c - 4;
        float m = 0.f;
        if ((unsigned)rr < 256u && (unsigned)cc < 256u) {
            float v = src[rr * 256 + cc];
            m = (v > tmin && v <= tmax) ? 1.f : 0.f;
        }
        mk[i][c] = m;
    }
    __syncthreads();
    // Phase B: P1 (pass1 h+v fused): thread c; rolling 9-row sum of P1h; /81 once.
    {
        int c = tid;
        auto hb = [&](int q) -> float {
            float s = 0.f;
#pragma unroll
            for (int k = 0; k < 9; ++k) s += mk[q][c + k];
            return s;
        };
        float w9[9]; float rs = 0.f;
#pragma unroll
        for (int q = 0; q < 8; ++q) { float h = hb(q); w9[q] = h; rs += h; }
#pragma unroll
        for (int pr = 0; pr < 31; ++pr) {
            int q = pr + 8;
            float h = hb(q); w9[q % 9] = h; rs += h;
            float val = rs * (1.f / 81.f);
            int ar = 2 * r0 - 8 + pr;
            if ((unsigned)ar >= 256u) val = 0.f;   // pass1 frame is 256 rows; outside = 0
            p1[pr][c + 4] = val;
            rs -= w9[pr % 9];
        }
    }
    if (tid < 248) { int i = tid >> 3, p = tid & 7; p1[i][p < 4 ? p : 256 + p] = 0.f; }
    __syncthreads();
    // Phase C: pass2 (h+v fused): thread c; rolling 9-row sum of p2h; /81; write into mk.
    {
        int c = tid;
        auto hb2 = [&](int q) -> float {
            float s = 0.f;
#pragma unroll
            for (int k = 0; k < 9; ++k) s += p1[q][c + k];
            return s;
        };
        float w9[9]; float rs = 0.f;
#pragma unroll
        for (int q = 0; q < 8; ++q) { float h = hb2(q); w9[q] = h; rs += h; }
#pragma unroll
        for (int i2 = 0; i2 < 23; ++i2) {
            int q = i2 + 8;
            float h = hb2(q); w9[q % 9] = h; rs += h;
            float val = rs * (1.f / 81.f);
            int ar = 2 * r0 - 4 + i2;
            if ((unsigned)ar >= 256u) val = 0.f;   // pass2 frame is 256 rows; outside = 0
            mk[i2][c + 4] = val;
            rs -= w9[i2 % 9];
        }
    }
    if (tid < 184) { int i2 = tid >> 3, p = tid & 7; mk[i2][p < 4 ? p : 256 + p] = 0.f; }
    __syncthreads();
    // Phase D: pass3 h-box stride2 -> p1[i2][ox] (23 x 128)
    for (int l = tid; l < 23 * 128; l += 256) {
        int i2 = l >> 7, ox = l & 127;
        float s = 0.f;
#pragma unroll
        for (int k = 0; k < 9; ++k) s += mk[i2][2 * ox + k];
        p1[i2][ox] = s * (1.f / 9.f);
    }
    __syncthreads();
    // Phase E: pass3 v-box stride2 + minmax + store
    float vmn = 1e30f, vmx = -1e30f;
    float* dst = p2 + (size_t)plane * 16384;
#pragma unroll
    for (int q = 0; q < 4; ++q) {
        int l = tid + 256 * q;
        int jj = l >> 7, ox = l & 127;
        float s = 0.f;
#pragma unroll
        for (int k = 0; k < 9; ++k) s += p1[2 * jj + k][ox];
        s *= (1.f / 9.f);
        dst[(r0 + jj) * 128 + ox] = s;
        vmn = fminf(vmn, s); vmx = fmaxf(vmx, s);
    }
    __syncthreads();
    float* smn = &mk[0][0];
    float* smx = &mk[1][0];
    smn[tid] = vmn; smx[tid] = vmx; __syncthreads();
    for (int off = 128; off > 0; off >>= 1) {
        if (tid < off) {
            smn[tid] = fminf(smn[tid], smn[tid + off]);
            smx[tid] = fmaxf(smx[tid], smx[tid + off]);
        }
        __syncthreads();
    }
    if (tid == 0) {
        atomicMin(&mnb[plane], __float_as_uint(smn[0]));
        atomicMax(&mxb[plane], __float_as_uint(smx[0]));
    }
}

// ---- H2: r13 k_hge verbatim (512 thr, output-split, LDS-shared stencil, 2 ch/iter,
//      2 barriers/iter, FMA 4px x 8o). Norm folded at tile==64. ----
__global__ __launch_bounds__(512, 2) void k_hge(const float* __restrict__ feat,
                                                const float* __restrict__ At,
                                                const float* __restrict__ fcb,
                                                const float* __restrict__ p2,
                                                const unsigned* __restrict__ mnb,
                                                const unsigned* __restrict__ mxb,
                                                float* __restrict__ gdm,
                                                float* __restrict__ out) {
    int tile = blockIdx.x, b = blockIdx.y;
    int tid = threadIdx.x;
    if (tile == 64) {
        int base = b * 512 + tid;
#pragma unroll
        for (int q = 0; q < 40; ++q) {
            int i4 = base + 4096 * q;
            int idx = i4 * 4;
            int plane = idx >> 14;
            float mn = __uint_as_float(mnb[plane]), mx = __uint_as_float(mxb[plane]);
            float inv = 1.f / (mx - mn);
            float4 v = *(const float4*)&p2[idx];
            float4 o = {(v.x - mn) * inv, (v.y - mn) * inv, (v.z - mn) * inv, (v.w - mn) * inv};
            *(float4*)&gdm[idx] = o;
        }
        return;
    }
    int ty = (tile >> 3) * 16, tx = (tile & 7) * 16;
    int grp = tid >> 8, tg = tid & 255;
    __shared__ float ft[2][20][21];
    __shared__ float tl[2][5][256];
    __shared__ float al[2][2][5][64];
    int og = tg >> 6;
    int pl = tg & 63;
    float acc[4][8];
#pragma unroll
    for (int i = 0; i < 4; ++i)
#pragma unroll
        for (int j = 0; j < 8; ++j) acc[i][j] = 0.f;

    const float* cur[3];
    int str3[3];
    bool ok[3];
#pragma unroll
    for (int j = 0; j < 3; ++j) {
        int l = tid + 512 * j;
        cur[j] = nullptr; str3[j] = 0; ok[j] = false;
        if (l < 800) {
            int ch = (l >= 400); int rem = l - ch * 400;
            int r = rem / 20, cx = rem - r * 20;
            int gy = ty - 2 + r, gx = tx - 2 + cx;
            if ((unsigned)gy < 128u && (unsigned)gx < 128u) {
                cur[j] = feat + (((size_t)(b * 64 + ch)) << 14) + gy * 128 + gx;
                str3[j] = 2 << 14;
                ok[j] = true;
            }
        } else if (l < 1440) {
            int q = l - 800;
            int ch = (q >= 320); int k = q - ch * 320;
            cur[j] = At + (k >> 6) * 4096 + ch * 64 + (k & 63);
            str3[j] = 128;
            ok[j] = true;
        }
    }
    float pr[3];
#pragma unroll
    for (int j = 0; j < 3; ++j) pr[j] = ok[j] ? *cur[j] : 0.f;

    for (int g = 0; g < 32; ++g) {
        int buf = g & 1;
#pragma unroll
        for (int j = 0; j < 3; ++j) {
            int l = tid + 512 * j;
            if (l < 800) {
                int ch = (l >= 400); int rem = l - ch * 400;
                int r = rem / 20, cx = rem - r * 20;
                ft[ch][r][cx] = pr[j];
            } else if (l < 1440) {
                ((float*)al[buf])[l - 800] = pr[j];
            }
        }
        __syncthreads();
        if (g < 31) {
#pragma unroll
            for (int j = 0; j < 3; ++j) {
                if (ok[j]) { cur[j] += str3[j]; pr[j] = *cur[j]; }
            }
        }
        {
            int cy = (tg >> 4) + 2, cx = (tg & 15) + 2;
            int ch = grp;
            float fm2 = ft[ch][cy - 2][cx], f2p = ft[ch][cy + 2][cx];
            float fl2 = ft[ch][cy][cx - 2], fr2 = ft[ch][cy][cx + 2];
            float a  = ft[ch][cy - 1][cx - 1], bq = ft[ch][cy - 1][cx], cc = ft[ch][cy - 1][cx + 1];
            float dd = ft[ch][cy][cx - 1],     ee = ft[ch][cy][cx],     ffv = ft[ch][cy][cx + 1];
            float g_ = ft[ch][cy + 1][cx - 1], h  = ft[ch][cy + 1][cx], i2 = ft[ch][cy + 1][cx + 1];
            tl[ch][0][tg] = (a + 2.f * bq + cc) - (g_ + 2.f * h + i2);
            tl[ch][1][tg] = 2.f * a + bq + dd - ffv - h - 2.f * i2;
            tl[ch][2][tg] = (a - cc) + 2.f * (dd - ffv) + (g_ - i2);
            tl[ch][3][tg] = -bq - 2.f * cc + dd - ffv + 2.f * g_ + h;
            tl[ch][4][tg] = ee - 0.125f * (bq + dd + ffv + h)
                          - 0.0625f * (fm2 + a + cc + fl2 + fr2 + g_ + i2 + f2p);
        }
        __syncthreads();
#pragma unroll
        for (int ch = 0; ch < 2; ++ch) {
#pragma unroll
            for (int d = 0; d < 5; ++d) {
                float4 a0 = *(const float4*)&al[buf][ch][d][grp * 32 + og * 8];
                float4 a1 = *(const float4*)&al[buf][ch][d][grp * 32 + og * 8 + 4];
                float av[8] = {a0.x, a0.y, a0.z, a0.w, a1.x, a1.y, a1.z, a1.w};
#pragma unroll
                for (int pj = 0; pj < 4; ++pj) {
                    float tv = tl[ch][d][pl + 64 * pj];
#pragma unroll
                    for (int oi = 0; oi < 8; ++oi)
                        acc[pj][oi] = fmaf(av[oi], tv, acc[pj][oi]);
                }
            }
        }
    }
#pragma unroll
    for (int oi = 0; oi < 8; ++oi) {
        int o = grp * 32 + og * 8 + oi;
        float bias = fcb[o];
        float* dsto = out + (((size_t)(b * 64 + o)) << 14);
#pragma unroll
        for (int pj = 0; pj < 4; ++pj) {
            int pxl = pl + 64 * pj;
            dsto[(ty + (pxl >> 4)) * 128 + tx + (pxl & 15)] = acc[pj][oi] + bias;
        }
    }
}

extern "C" void kernel_launch(void* const* d_in, const int* in_sizes, int n_in,
                              void* d_out, int out_size, void* d_ws, size_t ws_size,
                              hipStream_t stream) {
    const float* x    = (const float*)d_in[0];
    const float* gdmw = (const float*)d_in[1];
    const float* convw= (const float*)d_in[2];
    const float* bng  = (const float*)d_in[3];
    const float* bnb  = (const float*)d_in[4];
    const float* bnm  = (const float*)d_in[5];
    const float* bnv  = (const float*)d_in[6];
    const float* feat = (const float*)d_in[7];
    const float* hw   = (const float*)d_in[8];
    const float* fcw  = (const float*)d_in[9];
    const float* fcb  = (const float*)d_in[10];
    float* out = (float*)d_out;
    float* ws  = (float*)d_ws;

    float* At   = ws + WS_AT;
    float* ysum = ws + WS_YSUM;
    unsigned* xmax = (unsigned*)(ws + WS_XMAX);
    int* hist   = (int*)(ws + WS_HIST);
    unsigned* mnb = (unsigned*)(ws + WS_MN);
    unsigned* mxb = (unsigned*)(ws + WS_MX);
    float* xp   = ws + WS_XP;
    float* ia   = ws + WS_IA;
    float* xgl  = ws + WS_XGL;
    float* p2   = ws + WS_XP + 20480;

    float* hge = out + GDM_OUT;

    k_front  <<<2129, 256, 0, stream>>>(x, hw, fcw, xp, ia, At, ws + WS_YSUM, mnb, mxb);
    k_convgl <<<2560, 256, 0, stream>>>(xp, convw, ysum, ia, gdmw, xgl, hist, xmax);
    k_pool   <<<dim3(16, 40), 256, 0, stream>>>(xgl, ysum, bng, bnb, bnm, bnv, hist, xmax,
                                                p2, mnb, mxb);
    k_hge    <<<dim3(65, 8), 512, 0, stream>>>(feat, At, fcb, p2, mnb, mxb, out, hge);
}

// Round 15
// 214.163 us; speedup vs baseline: 1.4249x; 1.1304x over previous
//
#include <hip/hip_runtime.h>
#include <hip/hip_bf16.h>
#include <math.h>

// ---------------- workspace layout (floats) ----------------
#define WS_AT    0            // At fp32 20480 (dedicated)
#define WS_YSUM  20480        // 40
#define WS_XMAX  20520        // 8
#define WS_HIST  20528        // 816 (int)
#define WS_MN    21376        // 40 (uint)
#define WS_MX    21440        // 40 (uint)
#define WS_XP    21504        // 8*3*256*256 = 1572864
#define WS_IA    1594368      // 8*256*256   = 524288
#define WS_XGL   2118656      // 8*256*256   = 524288
// P2 = ws + WS_XP + 20480 (1310720 floats, inside xp region, written after k_mega)

#define GDM_OUT  655360       // 8*5*128*128

static __device__ __forceinline__ float xv_val(int i) {
    double t = (double)i / 100.0;
    return (float)(10.0 * t * t * t);
}

// ---- F1: fused [pool3+mean | mixA | zero/init accumulators] ----
__global__ __launch_bounds__(256) void k_front(const float* __restrict__ x,
                                               const float* __restrict__ hw,
                                               const float* __restrict__ fcw,
                                               float* __restrict__ xp,
                                               float* __restrict__ ia,
                                               float* __restrict__ At,
                                               float* __restrict__ zr,
                                               unsigned* __restrict__ mnb,
                                               unsigned* __restrict__ mxb) {
    int bid = blockIdx.x;
    if (bid < 2048) {
        int idx = bid * 256 + threadIdx.x;
        int b = idx >> 16; int p = idx & 65535; int oy = p >> 8; int ox = p & 255;
        float cs[3];
#pragma unroll
        for (int c = 0; c < 3; ++c) {
            const float* src = x + (((size_t)(b * 3 + c)) << 18);
            float s = 0.f;
#pragma unroll
            for (int dy = -1; dy <= 1; ++dy) {
                int iy = 2 * oy + dy; if ((unsigned)iy >= 512u) continue;
#pragma unroll
                for (int dx = -1; dx <= 1; ++dx) {
                    int ix = 2 * ox + dx; if ((unsigned)ix >= 512u) continue;
                    s += src[iy * 512 + ix];
                }
            }
            cs[c] = s * (1.f / 9.f);
            xp[(((size_t)(b * 3 + c)) << 16) + p] = cs[c];
        }
        ia[(((size_t)b) << 16) + p] = (cs[0] + cs[1] + cs[2]) * (1.f / 3.f);
    } else if (bid < 2128) {
        int idx = (bid - 2048) * 256 + threadIdx.x;   // 20480
        int o = idx & 63; int k = idx >> 6;           // k = d*64+c
        int d = k >> 6; int c = k & 63;
        const int goff[5] = {0, 1, 2, 3, 8};
        float s = 0.f;
        for (int m = 0; m < 64; ++m)
            s += fcw[o * 320 + d * 64 + m] * hw[(m * 64 + c) * 9 + goff[d]];
        At[k * 64 + o] = s * ((d == 4) ? 4.f : 1.f);
    } else {
#pragma unroll
        for (int q = 0; q < 4; ++q) {
            int i = threadIdx.x + 256 * q;
            if (i < 864) zr[i] = 0.f;
        }
        if (threadIdx.x < 40) mnb[threadIdx.x] = 0x7f7fffffu;
        else if (threadIdx.x < 80) mxb[threadIdx.x - 40] = 0u;
    }
}

// ---- MEGA: [conv7 (256 blk) | GL+hist (1024 blk) | hge main tiles (512 blk)], 512 thr ----
// convgl blocks placed first so their short memory-heavy work starts immediately and the
// ~120us hge tiles backfill; both halves depend only on k_front outputs (order-independent).
__global__ __launch_bounds__(512, 2) void k_mega(const float* __restrict__ xp,
                                                 const float* __restrict__ w,
                                                 float* __restrict__ ysum,
                                                 const float* __restrict__ ia,
                                                 const float* __restrict__ gdmw,
                                                 float* __restrict__ xgl,
                                                 int* __restrict__ hist,
                                                 unsigned* __restrict__ xmax,
                                                 const float* __restrict__ feat,
                                                 const float* __restrict__ At,
                                                 const float* __restrict__ fcb,
                                                 float* __restrict__ out) {
    __shared__ float wsm[735];
    __shared__ float red[512];
    __shared__ float xv[101];
    __shared__ int sh[102];
    __shared__ float ft[2][20][21];
    __shared__ float tl[2][5][256];
    __shared__ float al[2][2][5][64];
    int bid = blockIdx.x;
    int tid = threadIdx.x;
    if (bid < 256) {
        // conv7x7 s2 p3, all 5 cos, spatial sum; 512 thr, 32 blocks per b
        int b = bid >> 5;
        int p = (bid & 31) * 512 + tid;              // 16384 px per b
        int oy = p >> 7, ox = p & 127;
        for (int l = tid; l < 735; l += 512) wsm[l] = w[l];
        __syncthreads();
        float s[5] = {0.f, 0.f, 0.f, 0.f, 0.f};
        for (int ic = 0; ic < 3; ++ic) {
            const float* src = xp + (((size_t)(b * 3 + ic)) << 16);
#pragma unroll
            for (int r = 0; r < 7; ++r) {
                int iy = 2 * oy - 3 + r; if ((unsigned)iy >= 256u) continue;
#pragma unroll
                for (int ss = 0; ss < 7; ++ss) {
                    int ix = 2 * ox - 3 + ss; if ((unsigned)ix >= 256u) continue;
                    float v = src[iy * 256 + ix];
                    int wi = (ic * 7 + r) * 7 + ss;
#pragma unroll
                    for (int co = 0; co < 5; ++co) s[co] = fmaf(wsm[co * 147 + wi], v, s[co]);
                }
            }
        }
#pragma unroll
        for (int co = 0; co < 5; ++co) {
            red[tid] = s[co]; __syncthreads();
            for (int off = 256; off > 0; off >>= 1) {
                if (tid < off) red[tid] += red[tid + off];
                __syncthreads();
            }
            if (tid == 0) atomicAdd(&ysum[b * 5 + co], red[0]);
            __syncthreads();
        }
    } else if (bid < 1280) {
        // GL stencil + histogram + per-b max; 512 thr, 128 blocks per b
        int idx = bid - 256;
        int b = idx >> 7;
        int p = (idx & 127) * 512 + tid;             // 65536 px per b
        int y = p >> 8, x = p & 255;
        if (tid < 101) xv[tid] = xv_val(tid);
        if (tid < 102) sh[tid] = 0;
        __syncthreads();
        const float* src = ia + (((size_t)b) << 16);
        float a1 = gdmw[0] * 4.f;
        auto rd = [&](int dy, int dx) -> float {
            int iy = y + dy, ix = x + dx;
            if ((unsigned)iy >= 256u || (unsigned)ix >= 256u) return 0.f;
            return src[iy * 256 + ix];
        };
        float acc = rd(0, 0)
            - 0.125f  * (rd(-1, 0) + rd(0, -1) + rd(0, 1) + rd(1, 0))
            - 0.0625f * (rd(-2, 0) + rd(-1, -1) + rd(-1, 1) + rd(0, -2) +
                         rd(0, 2) + rd(1, -1) + rd(1, 1) + rd(2, 0));
        float raw = fabsf(a1 * acc);
        float val = (raw < 1e-6f) ? 0.f : raw;
        xgl[(((size_t)b) << 16) + p] = val;
        if (val > 0.f) {
            int lo = 0, hi = 101;
            while (lo < hi) { int mid = (lo + hi) >> 1; if (val <= xv[mid]) hi = mid; else lo = mid + 1; }
            atomicAdd(&sh[lo], 1);
        }
        red[tid] = val; __syncthreads();
        for (int off = 256; off > 0; off >>= 1) {
            if (tid < off) red[tid] = fmaxf(red[tid], red[tid + off]);
            __syncthreads();
        }
        if (tid == 0) atomicMax(&xmax[b], __float_as_uint(red[0]));
        if (tid < 102 && sh[tid]) atomicAdd(&hist[b * 102 + tid], sh[tid]);
    } else {
        // hge main tile (r13-verbatim)
        int hb = bid - 1280;
        int tile = hb & 63, b = hb >> 6;
        int ty = (tile >> 3) * 16, tx = (tile & 7) * 16;
        int grp = tid >> 8, tg = tid & 255;
        int og = tg >> 6;
        int pl = tg & 63;
        float acc[4][8];
#pragma unroll
        for (int i = 0; i < 4; ++i)
#pragma unroll
            for (int j = 0; j < 8; ++j) acc[i][j] = 0.f;

        const float* cur[3];
        int str3[3];
        bool ok[3];
#pragma unroll
        for (int j = 0; j < 3; ++j) {
            int l = tid + 512 * j;
            cur[j] = nullptr; str3[j] = 0; ok[j] = false;
            if (l < 800) {
                int ch = (l >= 400); int rem = l - ch * 400;
                int r = rem / 20, cx = rem - r * 20;
                int gy = ty - 2 + r, gx = tx - 2 + cx;
                if ((unsigned)gy < 128u && (unsigned)gx < 128u) {
                    cur[j] = feat + (((size_t)(b * 64 + ch)) << 14) + gy * 128 + gx;
                    str3[j] = 2 << 14;
                    ok[j] = true;
                }
            } else if (l < 1440) {
                int q = l - 800;
                int ch = (q >= 320); int k = q - ch * 320;
                cur[j] = At + (k >> 6) * 4096 + ch * 64 + (k & 63);
                str3[j] = 128;
                ok[j] = true;
            }
        }
        float pr[3];
#pragma unroll
        for (int j = 0; j < 3; ++j) pr[j] = ok[j] ? *cur[j] : 0.f;

        for (int g = 0; g < 32; ++g) {
            int buf = g & 1;
#pragma unroll
            for (int j = 0; j < 3; ++j) {
                int l = tid + 512 * j;
                if (l < 800) {
                    int ch = (l >= 400); int rem = l - ch * 400;
                    int r = rem / 20, cx = rem - r * 20;
                    ft[ch][r][cx] = pr[j];
                } else if (l < 1440) {
                    ((float*)al[buf])[l - 800] = pr[j];
                }
            }
            __syncthreads();
            if (g < 31) {
#pragma unroll
                for (int j = 0; j < 3; ++j) {
                    if (ok[j]) { cur[j] += str3[j]; pr[j] = *cur[j]; }
                }
            }
            {
                int cy = (tg >> 4) + 2, cx = (tg & 15) + 2;
                int ch = grp;
                float fm2 = ft[ch][cy - 2][cx], f2p = ft[ch][cy + 2][cx];
                float fl2 = ft[ch][cy][cx - 2], fr2 = ft[ch][cy][cx + 2];
                float a  = ft[ch][cy - 1][cx - 1], bq = ft[ch][cy - 1][cx], cc = ft[ch][cy - 1][cx + 1];
                float dd = ft[ch][cy][cx - 1],     ee = ft[ch][cy][cx],     ffv = ft[ch][cy][cx + 1];
                float g_ = ft[ch][cy + 1][cx - 1], h  = ft[ch][cy + 1][cx], i2 = ft[ch][cy + 1][cx + 1];
                tl[ch][0][tg] = (a + 2.f * bq + cc) - (g_ + 2.f * h + i2);
                tl[ch][1][tg] = 2.f * a + bq + dd - ffv - h - 2.f * i2;
                tl[ch][2][tg] = (a - cc) + 2.f * (dd - ffv) + (g_ - i2);
                tl[ch][3][tg] = -bq - 2.f * cc + dd - ffv + 2.f * g_ + h;
                tl[ch][4][tg] = ee - 0.125f * (bq + dd + ffv + h)
                              - 0.0625f * (fm2 + a + cc + fl2 + fr2 + g_ + i2 + f2p);
            }
            __syncthreads();
#pragma unroll
            for (int ch = 0; ch < 2; ++ch) {
#pragma unroll
                for (int d = 0; d < 5; ++d) {
                    float4 a0 = *(const float4*)&al[buf][ch][d][grp * 32 + og * 8];
                    float4 a1 = *(const float4*)&al[buf][ch][d][grp * 32 + og * 8 + 4];
                    float av[8] = {a0.x, a0.y, a0.z, a0.w, a1.x, a1.y, a1.z, a1.w};
#pragma unroll
                    for (int pj = 0; pj < 4; ++pj) {
                        float tv = tl[ch][d][pl + 64 * pj];
#pragma unroll
                        for (int oi = 0; oi < 8; ++oi)
                            acc[pj][oi] = fmaf(av[oi], tv, acc[pj][oi]);
                    }
                }
            }
        }
#pragma unroll
        for (int oi = 0; oi < 8; ++oi) {
            int o = grp * 32 + og * 8 + oi;
            float bias = fcb[o];
            float* dsto = out + (((size_t)(b * 64 + o)) << 14);
#pragma unroll
            for (int pj = 0; pj < 4; ++pj) {
                int pxl = pl + 64 * pj;
                dsto[(ty + (pxl >> 4)) * 128 + tx + (pxl & 15)] = acc[pj][oi] + bias;
            }
        }
    }
}

// ---- P: fused thresholds + mask + pass1 + pass2 + pass3 + minmax (r14-verbatim) ----
__global__ __launch_bounds__(256) void k_pool(const float* __restrict__ xgl,
                                              const float* __restrict__ ysum,
                                              const float* __restrict__ gamma,
                                              const float* __restrict__ beta,
                                              const float* __restrict__ mean,
                                              const float* __restrict__ var,
                                              const int* __restrict__ hist,
                                              const unsigned* __restrict__ xmax,
                                              float* __restrict__ p2,
                                              unsigned* __restrict__ mnb,
                                              unsigned* __restrict__ mxb) {
    int plane = blockIdx.y;
    int r0 = blockIdx.x * 8;
    int b = plane / 5, band = plane - 5 * b;
    __shared__ float mk[39][264];
    __shared__ float p1[31][264];
    __shared__ float sthr[4];
    int tid = threadIdx.x;
    if (tid == 0) {
        float wa[5];
        for (int c = 1; c < 5; ++c) {
            float m = ysum[b * 5 + c] * (1.f / 16384.f);
            wa[c] = tanhf((m - mean[c]) * rsqrtf(var[c] + 1e-5f) * gamma[c] + beta[c]);
        }
        float pr_[4] = {0.2f + 0.05f * wa[1], 0.4f + 0.05f * wa[2],
                        0.6f + 0.05f * wa[3], 0.8f + 0.05f * wa[4]};
        auto sw = [&](int i, int j) { if (pr_[i] > pr_[j]) { float t = pr_[i]; pr_[i] = pr_[j]; pr_[j] = t; } };
        sw(0, 1); sw(2, 3); sw(0, 2); sw(1, 3); sw(1, 2);
        int all = 0;
        for (int i = 0; i <= 101; ++i) all += hist[b * 102 + i];
        float bestz[4] = {1e30f, 1e30f, 1e30f, 1e30f};
        int besti[4] = {0, 0, 0, 0};
        int cum = 0;
        for (int i = 0; i <= 100; ++i) {
            cum += hist[b * 102 + i];
            float pct = (float)cum / (float)all;
            for (int t = 0; t < 4; ++t) {
                float z = fabsf(pct - pr_[t]);
                if (z < bestz[t]) { bestz[t] = z; besti[t] = i; }
            }
        }
        for (int t = 0; t < 4; ++t) sthr[t] = xv_val(besti[t]);
    }
    __syncthreads();
    float tmin = (band == 0) ? 0.f : sthr[band - 1];
    float tmax = (band == 4) ? __uint_as_float(xmax[b]) : sthr[band];
    const float* src = xgl + (((size_t)b) << 16);
    for (int l = tid; l < 39 * 264; l += 256) {
        int i = l / 264, c = l - i * 264;
        int rr = 2 * r0 - 12 + i, cc = c - 4;
        float m = 0.f;
        if ((unsigned)rr < 256u && (unsigned)cc < 256u) {
            float v = src[rr * 256 + cc];
            m = (v > tmin && v <= tmax) ? 1.f : 0.f;
        }
        mk[i][c] = m;
    }
    __syncthreads();
    {
        int c = tid;
        auto hb = [&](int q) -> float {
            float s = 0.f;
#pragma unroll
            for (int k = 0; k < 9; ++k) s += mk[q][c + k];
            return s;
        };
        float w9[9]; float rs = 0.f;
#pragma unroll
        for (int q = 0; q < 8; ++q) { float h = hb(q); w9[q] = h; rs += h; }
#pragma unroll
        for (int pr = 0; pr < 31; ++pr) {
            int q = pr + 8;
            float h = hb(q); w9[q % 9] = h; rs += h;
            float val = rs * (1.f / 81.f);
            int ar = 2 * r0 - 8 + pr;
            if ((unsigned)ar >= 256u) val = 0.f;
            p1[pr][c + 4] = val;
            rs -= w9[pr % 9];
        }
    }
    if (tid < 248) { int i = tid >> 3, p = tid & 7; p1[i][p < 4 ? p : 256 + p] = 0.f; }
    __syncthreads();
    {
        int c = tid;
        auto hb2 = [&](int q) -> float {
            float s = 0.f;
#pragma unroll
            for (int k = 0; k < 9; ++k) s += p1[q][c + k];
            return s;
        };
        float w9[9]; float rs = 0.f;
#pragma unroll
        for (int q = 0; q < 8; ++q) { float h = hb2(q); w9[q] = h; rs += h; }
#pragma unroll
        for (int i2 = 0; i2 < 23; ++i2) {
            int q = i2 + 8;
            float h = hb2(q); w9[q % 9] = h; rs += h;
            float val = rs * (1.f / 81.f);
            int ar = 2 * r0 - 4 + i2;
            if ((unsigned)ar >= 256u) val = 0.f;
            mk[i2][c + 4] = val;
            rs -= w9[i2 % 9];
        }
    }
    if (tid < 184) { int i2 = tid >> 3, p = tid & 7; mk[i2][p < 4 ? p : 256 + p] = 0.f; }
    __syncthreads();
    for (int l = tid; l < 23 * 128; l += 256) {
        int i2 = l >> 7, ox = l & 127;
        float s = 0.f;
#pragma unroll
        for (int k = 0; k < 9; ++k) s += mk[i2][2 * ox + k];
        p1[i2][ox] = s * (1.f / 9.f);
    }
    __syncthreads();
    float vmn = 1e30f, vmx = -1e30f;
    float* dst = p2 + (size_t)plane * 16384;
#pragma unroll
    for (int q = 0; q < 4; ++q) {
        int l = tid + 256 * q;
        int jj = l >> 7, ox = l & 127;
        float s = 0.f;
#pragma unroll
        for (int k = 0; k < 9; ++k) s += p1[2 * jj + k][ox];
        s *= (1.f / 9.f);
        dst[(r0 + jj) * 128 + ox] = s;
        vmn = fminf(vmn, s); vmx = fmaxf(vmx, s);
    }
    __syncthreads();
    float* smn = &mk[0][0];
    float* smx = &mk[1][0];
    smn[tid] = vmn; smx[tid] = vmx; __syncthreads();
    for (int off = 128; off > 0; off >>= 1) {
        if (tid < off) {
            smn[tid] = fminf(smn[tid], smn[tid + off]);
            smx[tid] = fmaxf(smx[tid], smx[tid + off]);
        }
        __syncthreads();
    }
    if (tid == 0) {
        atomicMin(&mnb[plane], __float_as_uint(smn[0]));
        atomicMax(&mxb[plane], __float_as_uint(smx[0]));
    }
}

// ---- normalize ----
__global__ __launch_bounds__(256) void k_norm(const float* __restrict__ in,
                                              const unsigned* __restrict__ mnb,
                                              const unsigned* __restrict__ mxb,
                                              float* __restrict__ gdm) {
    int i4 = blockIdx.x * 256 + threadIdx.x;
    int idx = i4 * 4;
    int plane = idx >> 14;
    float mn = __uint_as_float(mnb[plane]), mx = __uint_as_float(mxb[plane]);
    float inv = 1.f / (mx - mn);
    float4 v = *(const float4*)&in[idx];
    float4 o = {(v.x - mn) * inv, (v.y - mn) * inv, (v.z - mn) * inv, (v.w - mn) * inv};
    *(float4*)&gdm[idx] = o;
}

extern "C" void kernel_launch(void* const* d_in, const int* in_sizes, int n_in,
                              void* d_out, int out_size, void* d_ws, size_t ws_size,
                              hipStream_t stream) {
    const float* x    = (const float*)d_in[0];
    const float* gdmw = (const float*)d_in[1];
    const float* convw= (const float*)d_in[2];
    const float* bng  = (const float*)d_in[3];
    const float* bnb  = (const float*)d_in[4];
    const float* bnm  = (const float*)d_in[5];
    const float* bnv  = (const float*)d_in[6];
    const float* feat = (const float*)d_in[7];
    const float* hw   = (const float*)d_in[8];
    const float* fcw  = (const float*)d_in[9];
    const float* fcb  = (const float*)d_in[10];
    float* out = (float*)d_out;
    float* ws  = (float*)d_ws;

    float* At   = ws + WS_AT;
    float* ysum = ws + WS_YSUM;
    unsigned* xmax = (unsigned*)(ws + WS_XMAX);
    int* hist   = (int*)(ws + WS_HIST);
    unsigned* mnb = (unsigned*)(ws + WS_MN);
    unsigned* mxb = (unsigned*)(ws + WS_MX);
    float* xp   = ws + WS_XP;
    float* ia   = ws + WS_IA;
    float* xgl  = ws + WS_XGL;
    float* p2   = ws + WS_XP + 20480;

    float* hge = out + GDM_OUT;

    k_front <<<2129, 256, 0, stream>>>(x, hw, fcw, xp, ia, At, ws + WS_YSUM, mnb, mxb);
    k_mega  <<<1792, 512, 0, stream>>>(xp, convw, ysum, ia, gdmw, xgl, hist, xmax,
                                       feat, At, fcb, hge);
    k_pool  <<<dim3(16, 40), 256, 0, stream>>>(xgl, ysum, bng, bnb, bnm, bnv, hist, xmax,
                                               p2, mnb, mxb);
    k_norm  <<<640, 256, 0, stream>>>(p2, mnb, mxb, out);
}

// Round 16
// 206.079 us; speedup vs baseline: 1.4808x; 1.0392x over previous
//
#include <hip/hip_runtime.h>
#include <hip/hip_bf16.h>
#include <math.h>

// ---------------- workspace layout (floats) ----------------
#define WS_AT    0            // At fp32 20480 (dedicated)
#define WS_YSUM  20480        // 40
#define WS_XMAX  20520        // 8
#define WS_HIST  20528        // 816 (int)
#define WS_MN    21376        // 40 (uint)
#define WS_MX    21440        // 40 (uint)
#define WS_XP    21504        // 8*3*256*256 = 1572864
#define WS_IA    1594368      // 8*256*256   = 524288
#define WS_XGL   2118656      // 8*256*256   = 524288
// P2 = ws + WS_XP + 20480 (1310720 floats, inside xp region, written after k_mega)

#define GDM_OUT  655360       // 8*5*128*128

static __device__ __forceinline__ float xv_val(int i) {
    double t = (double)i / 100.0;
    return (float)(10.0 * t * t * t);
}

// ---- F1: fused [pool3+mean (LDS-staged, coalesced) | mixA | zero/init accumulators] ----
__global__ __launch_bounds__(256) void k_front(const float* __restrict__ x,
                                               const float* __restrict__ hw,
                                               const float* __restrict__ fcw,
                                               float* __restrict__ xp,
                                               float* __restrict__ ia,
                                               float* __restrict__ At,
                                               float* __restrict__ zr,
                                               unsigned* __restrict__ mnb,
                                               unsigned* __restrict__ mxb) {
    int bid = blockIdx.x;
    int tid = threadIdx.x;
    if (bid < 2048) {
        // one block per (b, output row oy); stage 9 input rows coalesced as float2
        int b = bid >> 8, oy = bid & 255;
        __shared__ float st[3][3][516];     // [ch][r][col+1], halo cols 0 and 513
#pragma unroll
        for (int q = 0; q < 9; ++q) {
            int ch = q / 3, r = q - 3 * (q / 3);
            int iy = 2 * oy - 1 + r;
            float2 v = {0.f, 0.f};
            if ((unsigned)iy < 512u)
                v = *(const float2*)&x[(((size_t)(b * 3 + ch)) << 18) + iy * 512 + 2 * tid];
            st[ch][r][1 + 2 * tid] = v.x;
            st[ch][r][2 + 2 * tid] = v.y;
        }
        if (tid < 9) { st[tid / 3][tid % 3][0] = 0.f; }
        else if (tid < 18) { int q = tid - 9; st[q / 3][q % 3][513] = 0.f; }
        __syncthreads();
        float cs[3];
#pragma unroll
        for (int ch = 0; ch < 3; ++ch) {
            float s = 0.f;
#pragma unroll
            for (int r = 0; r < 3; ++r)
#pragma unroll
                for (int k = 0; k < 3; ++k) s += st[ch][r][2 * tid + k];
            cs[ch] = s * (1.f / 9.f);
            xp[(((size_t)(b * 3 + ch)) << 16) + oy * 256 + tid] = cs[ch];
        }
        ia[(((size_t)b) << 16) + oy * 256 + tid] = (cs[0] + cs[1] + cs[2]) * (1.f / 3.f);
    } else if (bid < 2128) {
        int idx = (bid - 2048) * 256 + tid;           // 20480
        int o = idx & 63; int k = idx >> 6;           // k = d*64+c
        int d = k >> 6; int c = k & 63;
        const int goff[5] = {0, 1, 2, 3, 8};
        float s = 0.f;
        for (int m = 0; m < 64; ++m)
            s += fcw[o * 320 + d * 64 + m] * hw[(m * 64 + c) * 9 + goff[d]];
        At[k * 64 + o] = s * ((d == 4) ? 4.f : 1.f);
    } else {
#pragma unroll
        for (int q = 0; q < 4; ++q) {
            int i = tid + 256 * q;
            if (i < 864) zr[i] = 0.f;
        }
        if (tid < 40) mnb[tid] = 0x7f7fffffu;
        else if (tid < 80) mxb[tid - 40] = 0u;
    }
}

// ---- MEGA: [hge tiles FIRST (512 blk, LPT) | conv7 (256 blk) | GL+hist (1024 blk)] ----
__global__ __launch_bounds__(512, 2) void k_mega(const float* __restrict__ xp,
                                                 const float* __restrict__ w,
                                                 float* __restrict__ ysum,
                                                 const float* __restrict__ ia,
                                                 const float* __restrict__ gdmw,
                                                 float* __restrict__ xgl,
                                                 int* __restrict__ hist,
                                                 unsigned* __restrict__ xmax,
                                                 const float* __restrict__ feat,
                                                 const float* __restrict__ At,
                                                 const float* __restrict__ fcb,
                                                 float* __restrict__ out) {
    __shared__ float wsm[735];
    __shared__ float red[512];
    __shared__ float xv[101];
    __shared__ int sh[102];
    __shared__ float ft[2][20][21];
    __shared__ float tl[2][5][256];
    __shared__ float al[2][2][5][64];
    int bid = blockIdx.x;
    int tid = threadIdx.x;
    if (bid < 512) {
        // hge main tile (r13-verbatim), dispatched first (longest blocks)
        int hb = bid;
        int tile = hb & 63, b = hb >> 6;
        int ty = (tile >> 3) * 16, tx = (tile & 7) * 16;
        int grp = tid >> 8, tg = tid & 255;
        int og = tg >> 6;
        int pl = tg & 63;
        float acc[4][8];
#pragma unroll
        for (int i = 0; i < 4; ++i)
#pragma unroll
            for (int j = 0; j < 8; ++j) acc[i][j] = 0.f;

        const float* cur[3];
        int str3[3];
        bool ok[3];
#pragma unroll
        for (int j = 0; j < 3; ++j) {
            int l = tid + 512 * j;
            cur[j] = nullptr; str3[j] = 0; ok[j] = false;
            if (l < 800) {
                int ch = (l >= 400); int rem = l - ch * 400;
                int r = rem / 20, cx = rem - r * 20;
                int gy = ty - 2 + r, gx = tx - 2 + cx;
                if ((unsigned)gy < 128u && (unsigned)gx < 128u) {
                    cur[j] = feat + (((size_t)(b * 64 + ch)) << 14) + gy * 128 + gx;
                    str3[j] = 2 << 14;
                    ok[j] = true;
                }
            } else if (l < 1440) {
                int q = l - 800;
                int ch = (q >= 320); int k = q - ch * 320;
                cur[j] = At + (k >> 6) * 4096 + ch * 64 + (k & 63);
                str3[j] = 128;
                ok[j] = true;
            }
        }
        float pr[3];
#pragma unroll
        for (int j = 0; j < 3; ++j) pr[j] = ok[j] ? *cur[j] : 0.f;

        for (int g = 0; g < 32; ++g) {
            int buf = g & 1;
#pragma unroll
            for (int j = 0; j < 3; ++j) {
                int l = tid + 512 * j;
                if (l < 800) {
                    int ch = (l >= 400); int rem = l - ch * 400;
                    int r = rem / 20, cx = rem - r * 20;
                    ft[ch][r][cx] = pr[j];
                } else if (l < 1440) {
                    ((float*)al[buf])[l - 800] = pr[j];
                }
            }
            __syncthreads();
            if (g < 31) {
#pragma unroll
                for (int j = 0; j < 3; ++j) {
                    if (ok[j]) { cur[j] += str3[j]; pr[j] = *cur[j]; }
                }
            }
            {
                int cy = (tg >> 4) + 2, cx = (tg & 15) + 2;
                int ch = grp;
                float fm2 = ft[ch][cy - 2][cx], f2p = ft[ch][cy + 2][cx];
                float fl2 = ft[ch][cy][cx - 2], fr2 = ft[ch][cy][cx + 2];
                float a  = ft[ch][cy - 1][cx - 1], bq = ft[ch][cy - 1][cx], cc = ft[ch][cy - 1][cx + 1];
                float dd = ft[ch][cy][cx - 1],     ee = ft[ch][cy][cx],     ffv = ft[ch][cy][cx + 1];
                float g_ = ft[ch][cy + 1][cx - 1], h  = ft[ch][cy + 1][cx], i2 = ft[ch][cy + 1][cx + 1];
                tl[ch][0][tg] = (a + 2.f * bq + cc) - (g_ + 2.f * h + i2);
                tl[ch][1][tg] = 2.f * a + bq + dd - ffv - h - 2.f * i2;
                tl[ch][2][tg] = (a - cc) + 2.f * (dd - ffv) + (g_ - i2);
                tl[ch][3][tg] = -bq - 2.f * cc + dd - ffv + 2.f * g_ + h;
                tl[ch][4][tg] = ee - 0.125f * (bq + dd + ffv + h)
                              - 0.0625f * (fm2 + a + cc + fl2 + fr2 + g_ + i2 + f2p);
            }
            __syncthreads();
#pragma unroll
            for (int ch = 0; ch < 2; ++ch) {
#pragma unroll
                for (int d = 0; d < 5; ++d) {
                    float4 a0 = *(const float4*)&al[buf][ch][d][grp * 32 + og * 8];
                    float4 a1 = *(const float4*)&al[buf][ch][d][grp * 32 + og * 8 + 4];
                    float av[8] = {a0.x, a0.y, a0.z, a0.w, a1.x, a1.y, a1.z, a1.w};
#pragma unroll
                    for (int pj = 0; pj < 4; ++pj) {
                        float tv = tl[ch][d][pl + 64 * pj];
#pragma unroll
                        for (int oi = 0; oi < 8; ++oi)
                            acc[pj][oi] = fmaf(av[oi], tv, acc[pj][oi]);
                    }
                }
            }
        }
#pragma unroll
        for (int oi = 0; oi < 8; ++oi) {
            int o = grp * 32 + og * 8 + oi;
            float bias = fcb[o];
            float* dsto = out + (((size_t)(b * 64 + o)) << 14);
#pragma unroll
            for (int pj = 0; pj < 4; ++pj) {
                int pxl = pl + 64 * pj;
                dsto[(ty + (pxl >> 4)) * 128 + tx + (pxl & 15)] = acc[pj][oi] + bias;
            }
        }
    } else if (bid < 768) {
        // conv7x7 s2 p3, all 5 cos, spatial sum; 512 thr, 32 blocks per b
        int cb = bid - 512;
        int b = cb >> 5;
        int p = (cb & 31) * 512 + tid;
        int oy = p >> 7, ox = p & 127;
        for (int l = tid; l < 735; l += 512) wsm[l] = w[l];
        __syncthreads();
        float s[5] = {0.f, 0.f, 0.f, 0.f, 0.f};
        for (int ic = 0; ic < 3; ++ic) {
            const float* src = xp + (((size_t)(b * 3 + ic)) << 16);
#pragma unroll
            for (int r = 0; r < 7; ++r) {
                int iy = 2 * oy - 3 + r; if ((unsigned)iy >= 256u) continue;
#pragma unroll
                for (int ss = 0; ss < 7; ++ss) {
                    int ix = 2 * ox - 3 + ss; if ((unsigned)ix >= 256u) continue;
                    float v = src[iy * 256 + ix];
                    int wi = (ic * 7 + r) * 7 + ss;
#pragma unroll
                    for (int co = 0; co < 5; ++co) s[co] = fmaf(wsm[co * 147 + wi], v, s[co]);
                }
            }
        }
#pragma unroll
        for (int co = 0; co < 5; ++co) {
            red[tid] = s[co]; __syncthreads();
            for (int off = 256; off > 0; off >>= 1) {
                if (tid < off) red[tid] += red[tid + off];
                __syncthreads();
            }
            if (tid == 0) atomicAdd(&ysum[b * 5 + co], red[0]);
            __syncthreads();
        }
    } else {
        // GL stencil + histogram + per-b max; 512 thr, 128 blocks per b
        int idx = bid - 768;
        int b = idx >> 7;
        int p = (idx & 127) * 512 + tid;
        int y = p >> 8, x = p & 255;
        if (tid < 101) xv[tid] = xv_val(tid);
        if (tid < 102) sh[tid] = 0;
        __syncthreads();
        const float* src = ia + (((size_t)b) << 16);
        float a1 = gdmw[0] * 4.f;
        auto rd = [&](int dy, int dx) -> float {
            int iy = y + dy, ix = x + dx;
            if ((unsigned)iy >= 256u || (unsigned)ix >= 256u) return 0.f;
            return src[iy * 256 + ix];
        };
        float acc = rd(0, 0)
            - 0.125f  * (rd(-1, 0) + rd(0, -1) + rd(0, 1) + rd(1, 0))
            - 0.0625f * (rd(-2, 0) + rd(-1, -1) + rd(-1, 1) + rd(0, -2) +
                         rd(0, 2) + rd(1, -1) + rd(1, 1) + rd(2, 0));
        float raw = fabsf(a1 * acc);
        float val = (raw < 1e-6f) ? 0.f : raw;
        xgl[(((size_t)b) << 16) + p] = val;
        if (val > 0.f) {
            int lo = 0, hi = 101;
            while (lo < hi) { int mid = (lo + hi) >> 1; if (val <= xv[mid]) hi = mid; else lo = mid + 1; }
            atomicAdd(&sh[lo], 1);
        }
        red[tid] = val; __syncthreads();
        for (int off = 256; off > 0; off >>= 1) {
            if (tid < off) red[tid] = fmaxf(red[tid], red[tid + off]);
            __syncthreads();
        }
        if (tid == 0) atomicMax(&xmax[b], __float_as_uint(red[0]));
        if (tid < 102 && sh[tid]) atomicAdd(&hist[b * 102 + tid], sh[tid]);
    }
}

// ---- P: fused thresholds + mask + pass1 + pass2 + pass3 + minmax (r14-verbatim) ----
__global__ __launch_bounds__(256) void k_pool(const float* __restrict__ xgl,
                                              const float* __restrict__ ysum,
                                              const float* __restrict__ gamma,
                                              const float* __restrict__ beta,
                                              const float* __restrict__ mean,
                                              const float* __restrict__ var,
                                              const int* __restrict__ hist,
                                              const unsigned* __restrict__ xmax,
                                              float* __restrict__ p2,
                                              unsigned* __restrict__ mnb,
                                              unsigned* __restrict__ mxb) {
    int plane = blockIdx.y;
    int r0 = blockIdx.x * 8;
    int b = plane / 5, band = plane - 5 * b;
    __shared__ float mk[39][264];
    __shared__ float p1[31][264];
    __shared__ float sthr[4];
    int tid = threadIdx.x;
    if (tid == 0) {
        float wa[5];
        for (int c = 1; c < 5; ++c) {
            float m = ysum[b * 5 + c] * (1.f / 16384.f);
            wa[c] = tanhf((m - mean[c]) * rsqrtf(var[c] + 1e-5f) * gamma[c] + beta[c]);
        }
        float pr_[4] = {0.2f + 0.05f * wa[1], 0.4f + 0.05f * wa[2],
                        0.6f + 0.05f * wa[3], 0.8f + 0.05f * wa[4]};
        auto sw = [&](int i, int j) { if (pr_[i] > pr_[j]) { float t = pr_[i]; pr_[i] = pr_[j]; pr_[j] = t; } };
        sw(0, 1); sw(2, 3); sw(0, 2); sw(1, 3); sw(1, 2);
        int all = 0;
        for (int i = 0; i <= 101; ++i) all += hist[b * 102 + i];
        float bestz[4] = {1e30f, 1e30f, 1e30f, 1e30f};
        int besti[4] = {0, 0, 0, 0};
        int cum = 0;
        for (int i = 0; i <= 100; ++i) {
            cum += hist[b * 102 + i];
            float pct = (float)cum / (float)all;
            for (int t = 0; t < 4; ++t) {
                float z = fabsf(pct - pr_[t]);
                if (z < bestz[t]) { bestz[t] = z; besti[t] = i; }
            }
        }
        for (int t = 0; t < 4; ++t) sthr[t] = xv_val(besti[t]);
    }
    __syncthreads();
    float tmin = (band == 0) ? 0.f : sthr[band - 1];
    float tmax = (band == 4) ? __uint_as_float(xmax[b]) : sthr[band];
    const float* src = xgl + (((size_t)b) << 16);
    for (int l = tid; l < 39 * 264; l += 256) {
        int i = l / 264, c = l - i * 264;
        int rr = 2 * r0 - 12 + i, cc = c - 4;
        float m = 0.f;
        if ((unsigned)rr < 256u && (unsigned)cc < 256u) {
            float v = src[rr * 256 + cc];
            m = (v > tmin && v <= tmax) ? 1.f : 0.f;
        }
        mk[i][c] = m;
    }
    __syncthreads();
    {
        int c = tid;
        auto hb = [&](int q) -> float {
            float s = 0.f;
#pragma unroll
            for (int k = 0; k < 9; ++k) s += mk[q][c + k];
            return s;
        };
        float w9[9]; float rs = 0.f;
#pragma unroll
        for (int q = 0; q < 8; ++q) { float h = hb(q); w9[q] = h; rs += h; }
#pragma unroll
        for (int pr = 0; pr < 31; ++pr) {
            int q = pr + 8;
            float h = hb(q); w9[q % 9] = h; rs += h;
            float val = rs * (1.f / 81.f);
            int ar = 2 * r0 - 8 + pr;
            if ((unsigned)ar >= 256u) val = 0.f;
            p1[pr][c + 4] = val;
            rs -= w9[pr % 9];
        }
    }
    if (tid < 248) { int i = tid >> 3, p = tid & 7; p1[i][p < 4 ? p : 256 + p] = 0.f; }
    __syncthreads();
    {
        int c = tid;
        auto hb2 = [&](int q) -> float {
            float s = 0.f;
#pragma unroll
            for (int k = 0; k < 9; ++k) s += p1[q][c + k];
            return s;
        };
        float w9[9]; float rs = 0.f;
#pragma unroll
        for (int q = 0; q < 8; ++q) { float h = hb2(q); w9[q] = h; rs += h; }
#pragma unroll
        for (int i2 = 0; i2 < 23; ++i2) {
            int q = i2 + 8;
            float h = hb2(q); w9[q % 9] = h; rs += h;
            float val = rs * (1.f / 81.f);
            int ar = 2 * r0 - 4 + i2;
            if ((unsigned)ar >= 256u) val = 0.f;
            mk[i2][c + 4] = val;
            rs -= w9[i2 % 9];
        }
    }
    if (tid < 184) { int i2 = tid >> 3, p = tid & 7; mk[i2][p < 4 ? p : 256 + p] = 0.f; }
    __syncthreads();
    for (int l = tid; l < 23 * 128; l += 256) {
        int i2 = l >> 7, ox = l & 127;
        float s = 0.f;
#pragma unroll
        for (int k = 0; k < 9; ++k) s += mk[i2][2 * ox + k];
        p1[i2][ox] = s * (1.f / 9.f);
    }
    __syncthreads();
    float vmn = 1e30f, vmx = -1e30f;
    float* dst = p2 + (size_t)plane * 16384;
#pragma unroll
    for (int q = 0; q < 4; ++q) {
        int l = tid + 256 * q;
        int jj = l >> 7, ox = l & 127;
        float s = 0.f;
#pragma unroll
        for (int k = 0; k < 9; ++k) s += p1[2 * jj + k][ox];
        s *= (1.f / 9.f);
        dst[(r0 + jj) * 128 + ox] = s;
        vmn = fminf(vmn, s); vmx = fmaxf(vmx, s);
    }
    __syncthreads();
    float* smn = &mk[0][0];
    float* smx = &mk[1][0];
    smn[tid] = vmn; smx[tid] = vmx; __syncthreads();
    for (int off = 128; off > 0; off >>= 1) {
        if (tid < off) {
            smn[tid] = fminf(smn[tid], smn[tid + off]);
            smx[tid] = fmaxf(smx[tid], smx[tid + off]);
        }
        __syncthreads();
    }
    if (tid == 0) {
        atomicMin(&mnb[plane], __float_as_uint(smn[0]));
        atomicMax(&mxb[plane], __float_as_uint(smx[0]));
    }
}

// ---- normalize ----
__global__ __launch_bounds__(256) void k_norm(const float* __restrict__ in,
                                              const unsigned* __restrict__ mnb,
                                              const unsigned* __restrict__ mxb,
                                              float* __restrict__ gdm) {
    int i4 = blockIdx.x * 256 + threadIdx.x;
    int idx = i4 * 4;
    int plane = idx >> 14;
    float mn = __uint_as_float(mnb[plane]), mx = __uint_as_float(mxb[plane]);
    float inv = 1.f / (mx - mn);
    float4 v = *(const float4*)&in[idx];
    float4 o = {(v.x - mn) * inv, (v.y - mn) * inv, (v.z - mn) * inv, (v.w - mn) * inv};
    *(float4*)&gdm[idx] = o;
}

extern "C" void kernel_launch(void* const* d_in, const int* in_sizes, int n_in,
                              void* d_out, int out_size, void* d_ws, size_t ws_size,
                              hipStream_t stream) {
    const float* x    = (const float*)d_in[0];
    const float* gdmw = (const float*)d_in[1];
    const float* convw= (const float*)d_in[2];
    const float* bng  = (const float*)d_in[3];
    const float* bnb  = (const float*)d_in[4];
    const float* bnm  = (const float*)d_in[5];
    const float* bnv  = (const float*)d_in[6];
    const float* feat = (const float*)d_in[7];
    const float* hw   = (const float*)d_in[8];
    const float* fcw  = (const float*)d_in[9];
    const float* fcb  = (const float*)d_in[10];
    float* out = (float*)d_out;
    float* ws  = (float*)d_ws;

    float* At   = ws + WS_AT;
    float* ysum = ws + WS_YSUM;
    unsigned* xmax = (unsigned*)(ws + WS_XMAX);
    int* hist   = (int*)(ws + WS_HIST);
    unsigned* mnb = (unsigned*)(ws + WS_MN);
    unsigned* mxb = (unsigned*)(ws + WS_MX);
    float* xp   = ws + WS_XP;
    float* ia   = ws + WS_IA;
    float* xgl  = ws + WS_XGL;
    float* p2   = ws + WS_XP + 20480;

    float* hge = out + GDM_OUT;

    k_front <<<2129, 256, 0, stream>>>(x, hw, fcw, xp, ia, At, ws + WS_YSUM, mnb, mxb);
    k_mega  <<<1792, 512, 0, stream>>>(xp, convw, ysum, ia, gdmw, xgl, hist, xmax,
                                       feat, At, fcb, hge);
    k_pool  <<<dim3(16, 40), 256, 0, stream>>>(xgl, ysum, bng, bnb, bnm, bnv, hist, xmax,
                                               p2, mnb, mxb);
    k_norm  <<<640, 256, 0, stream>>>(p2, mnb, mxb, out);
}

// Round 17
// 202.758 us; speedup vs baseline: 1.5051x; 1.0164x over previous
//
#include <hip/hip_runtime.h>
#include <hip/hip_bf16.h>
#include <math.h>

// ---------------- workspace layout (floats) ----------------
#define WS_AT    0            // At fp32 20480 (dedicated)
#define WS_YSUM  20480        // 40
#define WS_XMAX  20520        // 8
#define WS_HIST  20528        // 816 (int)
#define WS_MN    21376        // 40 (uint)
#define WS_MX    21440        // 40 (uint)
#define WS_XP    21504        // 8*3*256*256 = 1572864
#define WS_IA    1594368      // 8*256*256   = 524288
#define WS_XGL   2118656      // 8*256*256   = 524288
// P2 = ws + WS_XP + 20480 (1310720 floats, inside xp region, written after k_mega)

#define GDM_OUT  655360       // 8*5*128*128

static __device__ __forceinline__ float xv_val(int i) {
    double t = (double)i / 100.0;
    return (float)(10.0 * t * t * t);
}

// ---- F1: fused [pool3+mean (LDS-staged, coalesced) | mixA | zero/init accumulators] ----
__global__ __launch_bounds__(256) void k_front(const float* __restrict__ x,
                                               const float* __restrict__ hw,
                                               const float* __restrict__ fcw,
                                               float* __restrict__ xp,
                                               float* __restrict__ ia,
                                               float* __restrict__ At,
                                               float* __restrict__ zr,
                                               unsigned* __restrict__ mnb,
                                               unsigned* __restrict__ mxb) {
    int bid = blockIdx.x;
    int tid = threadIdx.x;
    if (bid < 2048) {
        // one block per (b, output row oy); stage 9 input rows coalesced as float2
        int b = bid >> 8, oy = bid & 255;
        __shared__ float st[3][3][516];     // [ch][r][col+1], halo cols 0 and 513
#pragma unroll
        for (int q = 0; q < 9; ++q) {
            int ch = q / 3, r = q - 3 * (q / 3);
            int iy = 2 * oy - 1 + r;
            float2 v = {0.f, 0.f};
            if ((unsigned)iy < 512u)
                v = *(const float2*)&x[(((size_t)(b * 3 + ch)) << 18) + iy * 512 + 2 * tid];
            st[ch][r][1 + 2 * tid] = v.x;
            st[ch][r][2 + 2 * tid] = v.y;
        }
        if (tid < 9) { st[tid / 3][tid % 3][0] = 0.f; }
        else if (tid < 18) { int q = tid - 9; st[q / 3][q % 3][513] = 0.f; }
        __syncthreads();
        float cs[3];
#pragma unroll
        for (int ch = 0; ch < 3; ++ch) {
            float s = 0.f;
#pragma unroll
            for (int r = 0; r < 3; ++r)
#pragma unroll
                for (int k = 0; k < 3; ++k) s += st[ch][r][2 * tid + k];
            cs[ch] = s * (1.f / 9.f);
            xp[(((size_t)(b * 3 + ch)) << 16) + oy * 256 + tid] = cs[ch];
        }
        ia[(((size_t)b) << 16) + oy * 256 + tid] = (cs[0] + cs[1] + cs[2]) * (1.f / 3.f);
    } else if (bid < 2128) {
        int idx = (bid - 2048) * 256 + tid;           // 20480
        int o = idx & 63; int k = idx >> 6;           // k = d*64+c
        int d = k >> 6; int c = k & 63;
        const int goff[5] = {0, 1, 2, 3, 8};
        float s = 0.f;
        for (int m = 0; m < 64; ++m)
            s += fcw[o * 320 + d * 64 + m] * hw[(m * 64 + c) * 9 + goff[d]];
        At[k * 64 + o] = s * ((d == 4) ? 4.f : 1.f);
    } else {
#pragma unroll
        for (int q = 0; q < 4; ++q) {
            int i = tid + 256 * q;
            if (i < 864) zr[i] = 0.f;
        }
        if (tid < 40) mnb[tid] = 0x7f7fffffu;
        else if (tid < 80) mxb[tid - 40] = 0u;
    }
}

// ---- MEGA: [hge tiles FIRST (512 blk, LPT, 2-deep prefetch) | conv7 (256) | GL (1024)] ----
__global__ __launch_bounds__(512, 2) void k_mega(const float* __restrict__ xp,
                                                 const float* __restrict__ w,
                                                 float* __restrict__ ysum,
                                                 const float* __restrict__ ia,
                                                 const float* __restrict__ gdmw,
                                                 float* __restrict__ xgl,
                                                 int* __restrict__ hist,
                                                 unsigned* __restrict__ xmax,
                                                 const float* __restrict__ feat,
                                                 const float* __restrict__ At,
                                                 const float* __restrict__ fcb,
                                                 float* __restrict__ out) {
    __shared__ float wsm[735];
    __shared__ float red[512];
    __shared__ float xv[101];
    __shared__ int sh[102];
    __shared__ float ft[2][20][21];
    __shared__ float tl[2][5][256];
    __shared__ float al[2][2][5][64];
    int bid = blockIdx.x;
    int tid = threadIdx.x;
    if (bid < 512) {
        // hge main tile, dispatched first (longest blocks); 2-deep global prefetch
        int hb = bid;
        int tile = hb & 63, b = hb >> 6;
        int ty = (tile >> 3) * 16, tx = (tile & 7) * 16;
        int grp = tid >> 8, tg = tid & 255;
        int og = tg >> 6;
        int pl = tg & 63;
        float acc[4][8];
#pragma unroll
        for (int i = 0; i < 4; ++i)
#pragma unroll
            for (int j = 0; j < 8; ++j) acc[i][j] = 0.f;

        const float* cur[3];
        int str3[3];
        bool ok[3];
#pragma unroll
        for (int j = 0; j < 3; ++j) {
            int l = tid + 512 * j;
            cur[j] = nullptr; str3[j] = 0; ok[j] = false;
            if (l < 800) {
                int ch = (l >= 400); int rem = l - ch * 400;
                int r = rem / 20, cx = rem - r * 20;
                int gy = ty - 2 + r, gx = tx - 2 + cx;
                if ((unsigned)gy < 128u && (unsigned)gx < 128u) {
                    cur[j] = feat + (((size_t)(b * 64 + ch)) << 14) + gy * 128 + gx;
                    str3[j] = 2 << 14;
                    ok[j] = true;
                }
            } else if (l < 1440) {
                int q = l - 800;
                int ch = (q >= 320); int k = q - ch * 320;
                cur[j] = At + (k >> 6) * 4096 + ch * 64 + (k & 63);
                str3[j] = 128;
                ok[j] = true;
            }
        }
        // 2-deep prefetch: pf = iter g data, pf2 = iter g+1 data
        float pf[3], pf2[3];
#pragma unroll
        for (int j = 0; j < 3; ++j) {
            pf[j] = 0.f; pf2[j] = 0.f;
            if (ok[j]) { pf[j] = *cur[j]; cur[j] += str3[j];
                         pf2[j] = *cur[j]; cur[j] += str3[j]; }
        }

        for (int g = 0; g < 32; ++g) {
            int buf = g & 1;
#pragma unroll
            for (int j = 0; j < 3; ++j) {
                int l = tid + 512 * j;
                if (l < 800) {
                    int ch = (l >= 400); int rem = l - ch * 400;
                    int r = rem / 20, cx = rem - r * 20;
                    ft[ch][r][cx] = pf[j];
                } else if (l < 1440) {
                    ((float*)al[buf])[l - 800] = pf[j];
                }
            }
            __syncthreads();
            // rotate pipeline; issue load for iter g+2 (covers ~2 iters of HBM latency)
#pragma unroll
            for (int j = 0; j < 3; ++j) pf[j] = pf2[j];
            if (g < 30) {
#pragma unroll
                for (int j = 0; j < 3; ++j) {
                    if (ok[j]) { pf2[j] = *cur[j]; cur[j] += str3[j]; }
                }
            }
            {
                int cy = (tg >> 4) + 2, cx = (tg & 15) + 2;
                int ch = grp;
                float fm2 = ft[ch][cy - 2][cx], f2p = ft[ch][cy + 2][cx];
                float fl2 = ft[ch][cy][cx - 2], fr2 = ft[ch][cy][cx + 2];
                float a  = ft[ch][cy - 1][cx - 1], bq = ft[ch][cy - 1][cx], cc = ft[ch][cy - 1][cx + 1];
                float dd = ft[ch][cy][cx - 1],     ee = ft[ch][cy][cx],     ffv = ft[ch][cy][cx + 1];
                float g_ = ft[ch][cy + 1][cx - 1], h  = ft[ch][cy + 1][cx], i2 = ft[ch][cy + 1][cx + 1];
                tl[ch][0][tg] = (a + 2.f * bq + cc) - (g_ + 2.f * h + i2);
                tl[ch][1][tg] = 2.f * a + bq + dd - ffv - h - 2.f * i2;
                tl[ch][2][tg] = (a - cc) + 2.f * (dd - ffv) + (g_ - i2);
                tl[ch][3][tg] = -bq - 2.f * cc + dd - ffv + 2.f * g_ + h;
                tl[ch][4][tg] = ee - 0.125f * (bq + dd + ffv + h)
                              - 0.0625f * (fm2 + a + cc + fl2 + fr2 + g_ + i2 + f2p);
            }
            __syncthreads();
#pragma unroll
            for (int ch = 0; ch < 2; ++ch) {
#pragma unroll
                for (int d = 0; d < 5; ++d) {
                    float4 a0 = *(const float4*)&al[buf][ch][d][grp * 32 + og * 8];
                    float4 a1 = *(const float4*)&al[buf][ch][d][grp * 32 + og * 8 + 4];
                    float av[8] = {a0.x, a0.y, a0.z, a0.w, a1.x, a1.y, a1.z, a1.w};
#pragma unroll
                    for (int pj = 0; pj < 4; ++pj) {
                        float tv = tl[ch][d][pl + 64 * pj];
#pragma unroll
                        for (int oi = 0; oi < 8; ++oi)
                            acc[pj][oi] = fmaf(av[oi], tv, acc[pj][oi]);
                    }
                }
            }
        }
#pragma unroll
        for (int oi = 0; oi < 8; ++oi) {
            int o = grp * 32 + og * 8 + oi;
            float bias = fcb[o];
            float* dsto = out + (((size_t)(b * 64 + o)) << 14);
#pragma unroll
            for (int pj = 0; pj < 4; ++pj) {
                int pxl = pl + 64 * pj;
                dsto[(ty + (pxl >> 4)) * 128 + tx + (pxl & 15)] = acc[pj][oi] + bias;
            }
        }
    } else if (bid < 768) {
        // conv7x7 s2 p3, all 5 cos, spatial sum; 512 thr, 32 blocks per b
        int cb = bid - 512;
        int b = cb >> 5;
        int p = (cb & 31) * 512 + tid;
        int oy = p >> 7, ox = p & 127;
        for (int l = tid; l < 735; l += 512) wsm[l] = w[l];
        __syncthreads();
        float s[5] = {0.f, 0.f, 0.f, 0.f, 0.f};
        for (int ic = 0; ic < 3; ++ic) {
            const float* src = xp + (((size_t)(b * 3 + ic)) << 16);
#pragma unroll
            for (int r = 0; r < 7; ++r) {
                int iy = 2 * oy - 3 + r; if ((unsigned)iy >= 256u) continue;
#pragma unroll
                for (int ss = 0; ss < 7; ++ss) {
                    int ix = 2 * ox - 3 + ss; if ((unsigned)ix >= 256u) continue;
                    float v = src[iy * 256 + ix];
                    int wi = (ic * 7 + r) * 7 + ss;
#pragma unroll
                    for (int co = 0; co < 5; ++co) s[co] = fmaf(wsm[co * 147 + wi], v, s[co]);
                }
            }
        }
#pragma unroll
        for (int co = 0; co < 5; ++co) {
            red[tid] = s[co]; __syncthreads();
            for (int off = 256; off > 0; off >>= 1) {
                if (tid < off) red[tid] += red[tid + off];
                __syncthreads();
            }
            if (tid == 0) atomicAdd(&ysum[b * 5 + co], red[0]);
            __syncthreads();
        }
    } else {
        // GL stencil + histogram + per-b max; 512 thr, 128 blocks per b
        int idx = bid - 768;
        int b = idx >> 7;
        int p = (idx & 127) * 512 + tid;
        int y = p >> 8, x = p & 255;
        if (tid < 101) xv[tid] = xv_val(tid);
        if (tid < 102) sh[tid] = 0;
        __syncthreads();
        const float* src = ia + (((size_t)b) << 16);
        float a1 = gdmw[0] * 4.f;
        auto rd = [&](int dy, int dx) -> float {
            int iy = y + dy, ix = x + dx;
            if ((unsigned)iy >= 256u || (unsigned)ix >= 256u) return 0.f;
            return src[iy * 256 + ix];
        };
        float acc = rd(0, 0)
            - 0.125f  * (rd(-1, 0) + rd(0, -1) + rd(0, 1) + rd(1, 0))
            - 0.0625f * (rd(-2, 0) + rd(-1, -1) + rd(-1, 1) + rd(0, -2) +
                         rd(0, 2) + rd(1, -1) + rd(1, 1) + rd(2, 0));
        float raw = fabsf(a1 * acc);
        float val = (raw < 1e-6f) ? 0.f : raw;
        xgl[(((size_t)b) << 16) + p] = val;
        if (val > 0.f) {
            int lo = 0, hi = 101;
            while (lo < hi) { int mid = (lo + hi) >> 1; if (val <= xv[mid]) hi = mid; else lo = mid + 1; }
            atomicAdd(&sh[lo], 1);
        }
        red[tid] = val; __syncthreads();
        for (int off = 256; off > 0; off >>= 1) {
            if (tid < off) red[tid] = fmaxf(red[tid], red[tid + off]);
            __syncthreads();
        }
        if (tid == 0) atomicMax(&xmax[b], __float_as_uint(red[0]));
        if (tid < 102 && sh[tid]) atomicAdd(&hist[b * 102 + tid], sh[tid]);
    }
}

// ---- P: fused thresholds + mask + pass1 + pass2 + pass3 + minmax (r14-verbatim) ----
__global__ __launch_bounds__(256) void k_pool(const float* __restrict__ xgl,
                                              const float* __restrict__ ysum,
                                              const float* __restrict__ gamma,
                                              const float* __restrict__ beta,
                                              const float* __restrict__ mean,
                                              const float* __restrict__ var,
                                              const int* __restrict__ hist,
                                              const unsigned* __restrict__ xmax,
                                              float* __restrict__ p2,
                                              unsigned* __restrict__ mnb,
                                              unsigned* __restrict__ mxb) {
    int plane = blockIdx.y;
    int r0 = blockIdx.x * 8;
    int b = plane / 5, band = plane - 5 * b;
    __shared__ float mk[39][264];
    __shared__ float p1[31][264];
    __shared__ float sthr[4];
    int tid = threadIdx.x;
    if (tid == 0) {
        float wa[5];
        for (int c = 1; c < 5; ++c) {
            float m = ysum[b * 5 + c] * (1.f / 16384.f);
            wa[c] = tanhf((m - mean[c]) * rsqrtf(var[c] + 1e-5f) * gamma[c] + beta[c]);
        }
        float pr_[4] = {0.2f + 0.05f * wa[1], 0.4f + 0.05f * wa[2],
                        0.6f + 0.05f * wa[3], 0.8f + 0.05f * wa[4]};
        auto sw = [&](int i, int j) { if (pr_[i] > pr_[j]) { float t = pr_[i]; pr_[i] = pr_[j]; pr_[j] = t; } };
        sw(0, 1); sw(2, 3); sw(0, 2); sw(1, 3); sw(1, 2);
        int all = 0;
        for (int i = 0; i <= 101; ++i) all += hist[b * 102 + i];
        float bestz[4] = {1e30f, 1e30f, 1e30f, 1e30f};
        int besti[4] = {0, 0, 0, 0};
        int cum = 0;
        for (int i = 0; i <= 100; ++i) {
            cum += hist[b * 102 + i];
            float pct = (float)cum / (float)all;
            for (int t = 0; t < 4; ++t) {
                float z = fabsf(pct - pr_[t]);
                if (z < bestz[t]) { bestz[t] = z; besti[t] = i; }
            }
        }
        for (int t = 0; t < 4; ++t) sthr[t] = xv_val(besti[t]);
    }
    __syncthreads();
    float tmin = (band == 0) ? 0.f : sthr[band - 1];
    float tmax = (band == 4) ? __uint_as_float(xmax[b]) : sthr[band];
    const float* src = xgl + (((size_t)b) << 16);
    for (int l = tid; l < 39 * 264; l += 256) {
        int i = l / 264, c = l - i * 264;
        int rr = 2 * r0 - 12 + i, cc = c - 4;
        float m = 0.f;
        if ((unsigned)rr < 256u && (unsigned)cc < 256u) {
            float v = src[rr * 256 + cc];
            m = (v > tmin && v <= tmax) ? 1.f : 0.f;
        }
        mk[i][c] = m;
    }
    __syncthreads();
    {
        int c = tid;
        auto hb = [&](int q) -> float {
            float s = 0.f;
#pragma unroll
            for (int k = 0; k < 9; ++k) s += mk[q][c + k];
            return s;
        };
        float w9[9]; float rs = 0.f;
#pragma unroll
        for (int q = 0; q < 8; ++q) { float h = hb(q); w9[q] = h; rs += h; }
#pragma unroll
        for (int pr = 0; pr < 31; ++pr) {
            int q = pr + 8;
            float h = hb(q); w9[q % 9] = h; rs += h;
            float val = rs * (1.f / 81.f);
            int ar = 2 * r0 - 8 + pr;
            if ((unsigned)ar >= 256u) val = 0.f;
            p1[pr][c + 4] = val;
            rs -= w9[pr % 9];
        }
    }
    if (tid < 248) { int i = tid >> 3, p = tid & 7; p1[i][p < 4 ? p : 256 + p] = 0.f; }
    __syncthreads();
    {
        int c = tid;
        auto hb2 = [&](int q) -> float {
            float s = 0.f;
#pragma unroll
            for (int k = 0; k < 9; ++k) s += p1[q][c + k];
            return s;
        };
        float w9[9]; float rs = 0.f;
#pragma unroll
        for (int q = 0; q < 8; ++q) { float h = hb2(q); w9[q] = h; rs += h; }
#pragma unroll
        for (int i2 = 0; i2 < 23; ++i2) {
            int q = i2 + 8;
            float h = hb2(q); w9[q % 9] = h; rs += h;
            float val = rs * (1.f / 81.f);
            int ar = 2 * r0 - 4 + i2;
            if ((unsigned)ar >= 256u) val = 0.f;
            mk[i2][c + 4] = val;
            rs -= w9[i2 % 9];
        }
    }
    if (tid < 184) { int i2 = tid >> 3, p = tid & 7; mk[i2][p < 4 ? p : 256 + p] = 0.f; }
    __syncthreads();
    for (int l = tid; l < 23 * 128; l += 256) {
        int i2 = l >> 7, ox = l & 127;
        float s = 0.f;
#pragma unroll
        for (int k = 0; k < 9; ++k) s += mk[i2][2 * ox + k];
        p1[i2][ox] = s * (1.f / 9.f);
    }
    __syncthreads();
    float vmn = 1e30f, vmx = -1e30f;
    float* dst = p2 + (size_t)plane * 16384;
#pragma unroll
    for (int q = 0; q < 4; ++q) {
        int l = tid + 256 * q;
        int jj = l >> 7, ox = l & 127;
        float s = 0.f;
#pragma unroll
        for (int k = 0; k < 9; ++k) s += p1[2 * jj + k][ox];
        s *= (1.f / 9.f);
        dst[(r0 + jj) * 128 + ox] = s;
        vmn = fminf(vmn, s); vmx = fmaxf(vmx, s);
    }
    __syncthreads();
    float* smn = &mk[0][0];
    float* smx = &mk[1][0];
    smn[tid] = vmn; smx[tid] = vmx; __syncthreads();
    for (int off = 128; off > 0; off >>= 1) {
        if (tid < off) {
            smn[tid] = fminf(smn[tid], smn[tid + off]);
            smx[tid] = fmaxf(smx[tid], smx[tid + off]);
        }
        __syncthreads();
    }
    if (tid == 0) {
        atomicMin(&mnb[plane], __float_as_uint(smn[0]));
        atomicMax(&mxb[plane], __float_as_uint(smx[0]));
    }
}

// ---- normalize ----
__global__ __launch_bounds__(256) void k_norm(const float* __restrict__ in,
                                              const unsigned* __restrict__ mnb,
                                              const unsigned* __restrict__ mxb,
                                              float* __restrict__ gdm) {
    int i4 = blockIdx.x * 256 + threadIdx.x;
    int idx = i4 * 4;
    int plane = idx >> 14;
    float mn = __uint_as_float(mnb[plane]), mx = __uint_as_float(mxb[plane]);
    float inv = 1.f / (mx - mn);
    float4 v = *(const float4*)&in[idx];
    float4 o = {(v.x - mn) * inv, (v.y - mn) * inv, (v.z - mn) * inv, (v.w - mn) * inv};
    *(float4*)&gdm[idx] = o;
}

extern "C" void kernel_launch(void* const* d_in, const int* in_sizes, int n_in,
                              void* d_out, int out_size, void* d_ws, size_t ws_size,
                              hipStream_t stream) {
    const float* x    = (const float*)d_in[0];
    const float* gdmw = (const float*)d_in[1];
    const float* convw= (const float*)d_in[2];
    const float* bng  = (const float*)d_in[3];
    const float* bnb  = (const float*)d_in[4];
    const float* bnm  = (const float*)d_in[5];
    const float* bnv  = (const float*)d_in[6];
    const float* feat = (const float*)d_in[7];
    const float* hw   = (const float*)d_in[8];
    const float* fcw  = (const float*)d_in[9];
    const float* fcb  = (const float*)d_in[10];
    float* out = (float*)d_out;
    float* ws  = (float*)d_ws;

    float* At   = ws + WS_AT;
    float* ysum = ws + WS_YSUM;
    unsigned* xmax = (unsigned*)(ws + WS_XMAX);
    int* hist   = (int*)(ws + WS_HIST);
    unsigned* mnb = (unsigned*)(ws + WS_MN);
    unsigned* mxb = (unsigned*)(ws + WS_MX);
    float* xp   = ws + WS_XP;
    float* ia   = ws + WS_IA;
    float* xgl  = ws + WS_XGL;
    float* p2   = ws + WS_XP + 20480;

    float* hge = out + GDM_OUT;

    k_front <<<2129, 256, 0, stream>>>(x, hw, fcw, xp, ia, At, ws + WS_YSUM, mnb, mxb);
    k_mega  <<<1792, 512, 0, stream>>>(xp, convw, ysum, ia, gdmw, xgl, hist, xmax,
                                       feat, At, fcb, hge);
    k_pool  <<<dim3(16, 40), 256, 0, stream>>>(xgl, ysum, bng, bnb, bnm, bnv, hist, xmax,
                                               p2, mnb, mxb);
    k_norm  <<<640, 256, 0, stream>>>(p2, mnb, mxb, out);
}